// Round 3
// baseline (523.018 us; speedup 1.0000x reference)
//
#include <hip/hip_runtime.h>
#include <hip/hip_bf16.h>

#define BATCH 8192
#define IN_DIM 64
#define HID 1024
#define KTOT 1088   // HID + IN_DIM (fused K; weights laid out [n][KTOT])
#define NGATES 4096 // 4*HID, column c = 64*G + 16*g + q -> gate g of h=16*G+q
#define OMID 128
#define NP 256      // packed P rows (W1 0..127, W_halt 128, zeros)
#define MAX_ITER 8

#define TM 128
#define TN 128
#define TK 64
#define GTM 256     // gates_k m-tile (R14: 256^2 2-phase double-buffered)
#define GTN 256     // gates_k n-tile
#define TAILB 64    // tail_k blocks: few enough that a device barrier is cheap

typedef __attribute__((ext_vector_type(8))) short short8;
typedef __attribute__((ext_vector_type(4))) float float4v;

__device__ __forceinline__ float bf2f(short s) {
    union { float f; unsigned u; } v; v.u = ((unsigned)(unsigned short)s) << 16; return v.f;
}
__device__ __forceinline__ short f2bf(float f) {
    union { float f; unsigned u; } v; v.f = f;
    unsigned r = v.u + 0x7fff + ((v.u >> 16) & 1);  // round-to-nearest-even
    return (short)(r >> 16);
}
__device__ __forceinline__ float sigmoidf_(float x) {
    float xc = fminf(fmaxf(x, -30.f), 30.f);
    return 1.f / (1.f + __expf(-xc));
}
__device__ __forceinline__ float tanhf_(float x) {
    float xc = fminf(fmaxf(x, -15.f), 15.f);
    float e = __expf(2.f * xc);
    return (e - 1.f) / (e + 1.f);
}
__device__ __forceinline__ int aload(const int* p) {
    return __hip_atomic_load((int*)p, __ATOMIC_RELAXED, __HIP_MEMORY_SCOPE_AGENT);
}
__device__ __forceinline__ void astore(int* p, int v) {
    __hip_atomic_store(p, v, __ATOMIC_RELAXED, __HIP_MEMORY_SCOPE_AGENT);
}

// 64-block generation barrier (R8-verified; R5/R7/R11: ANY wider barrier
// pays 50-100us in cross-XCD L2 invalidate traffic). RELAXED polling by one
// lane per block with s_sleep; fences only at the crossing points.
__device__ __forceinline__ void gbar(int* bar, int phase, int tid) {
    __syncthreads();
    if (tid == 0) {
        __threadfence();
        __hip_atomic_fetch_add(bar, 1, __ATOMIC_ACQ_REL, __HIP_MEMORY_SCOPE_AGENT);
        while (aload(bar) < TAILB * phase)
            __builtin_amdgcn_s_sleep(8);
        __threadfence();
    }
    __syncthreads();
}

// Shared epilogue: fused LSTM cell update for one 128-row m-tile's
// accumulators (used by the 128^2 gates_tile inside tail_k).
// first=1 (t==0): cell is write-only (c = i*cg == f*0 + i*cg bit-exactly),
// so cell never needs zero-init and t=0 skips the 33.6MB cell read.
__device__ __forceinline__ void gates_epilogue(
    const float4v (&acc)[4][4], int m0, int bx, int wave, int lane, int first,
    const float* __restrict__ bias_g, float* __restrict__ cell,
    short* __restrict__ Sout, const int* __restrict__ ridx, int n_act)
{
    const int wm = wave & 1, wn = wave >> 1;
    const int colq = lane & 15, q = lane >> 4;
    const int G = bx * 2 + wn;   // 64-col group = 16 hidden units
    const int h = G * 16 + colq;
    const float bi  = bias_g[G * 64 +  0 + colq];
    const float bff = bias_g[G * 64 + 16 + colq];
    const float bc  = bias_g[G * 64 + 32 + colq];
    const float bo  = bias_g[G * 64 + 48 + colq];
#pragma unroll
    for (int i = 0; i < 4; ++i) {
        const int pbase = m0 + wm * 64 + i * 16 + q * 4;
#pragma unroll
        for (int r = 0; r < 4; ++r) {
            const int pos = pbase + r;
            if (pos < n_act) {
                const int row = ridx[pos];
                const float ig = sigmoidf_(acc[i][0][r] + bi);
                const float fg = sigmoidf_(acc[i][1][r] + bff);
                const float cg = tanhf_(acc[i][2][r] + bc);
                const float og = sigmoidf_(acc[i][3][r] + bo);
                const size_t ci = (size_t)row * HID + h;
                const float c = first ? (ig * cg) : (fg * cell[ci] + ig * cg);
                cell[ci] = c;
                Sout[(size_t)row * HID + h] = f2bf(og * tanhf_(c));
            }
        }
    }
}

// Gates GEMM, R15 structure: 256x256 tile, 8 waves (2M x 4N), BK=64,
// double-buffered LDS, COUNTED-VMCNT PIPELINE (guide T4; m218: counted
// vs drain-0 = +38-73%). R14 measured 117.7us / MfmaUtil 25.8 with
// __syncthreads per K-step: the compiler's barrier drains vmcnt(0),
// including the just-issued prefetch -> serial L2 round-trip per K-step.
// New schedule per K-step: ds_read frags(buf[cur]) -> [lgkmcnt(0)+bar ->
// restage ki+2 INTO buf[cur]] -> 64 MFMA -> vmcnt(8) (wait ONLY the
// oldest 8 = stage(ki+1); leave ki+2's 8 in flight) + bar. Every wave
// waits its own oldest loads before the barrier => buffer collectively
// ready after it. All barriers in kernel-uniform control flow.
// SPLIT A LAYOUT kept (S + XB, final K-chunk from XB, uniform branch).
// LDS XOR swizzle kept (R2: 0 conflicts).
__global__ __launch_bounds__(512, 1) void gates_k(
    const short* __restrict__ S, const short* __restrict__ XB,
    const short* __restrict__ B,
    const float* __restrict__ bias_g, int nK, int hidK, int first,
    float* __restrict__ cell, short* __restrict__ Sout,
    const int* __restrict__ ridx, const int* __restrict__ cnt, int t)
{
    __shared__ short As[2][GTM * TK];   // 2 x 32 KiB
    __shared__ short Bs[2][GTN * TK];   // 2 x 32 KiB
    const int n_act = cnt[t];
    const int tid  = threadIdx.x;
    const int wave = tid >> 6, lane = tid & 63;
    const int wm2 = wave >> 2, wn4 = wave & 3;   // wave -> 128-row half x 64-col quarter
    const int colq = lane & 15, q = lane >> 4;
    const int lrow8 = lane >> 3;
    const int lk    = (((lane & 7) ^ lrow8) * 8);   // pre-swizzled source offset
    const int n0 = blockIdx.x * GTN;
    const int xq = colq & 7;
    const int abase = (wm2 * 128 + colq) * TK;   // shorts
    const int bbase = (wn4 * 64  + colq) * TK;   // shorts

    for (int by = blockIdx.y; by * GTM < n_act; by += gridDim.y) {
        const int m0 = by * GTM;

        // per-wave staged rows: wave*32 + it*8 + lrow8 (A and B share the map)
        int rows_[4];
        const short* gb[4];
#pragma unroll
        for (int it = 0; it < 4; ++it) {
            const int rr = wave * 32 + it * 8 + lrow8;
            rows_[it] = ridx[m0 + rr];
            gb[it] = B + (size_t)(n0 + rr) * KTOT + lk;
        }

        float4v acc[8][4];
#pragma unroll
        for (int i = 0; i < 8; ++i)
#pragma unroll
            for (int j = 0; j < 4; ++j) acc[i][j] = (float4v)0.f;

        auto stage = [&](int ki, int buf) {
            const int kk = ki * TK;
            const bool fromS = (kk < hidK);   // kernel-uniform branch
#pragma unroll
            for (int it = 0; it < 4; ++it) {
                const int dst = (wave * 32 + it * 8) * TK;
                const short* sa = fromS
                    ? (S  + (size_t)rows_[it] * HID    + kk + lk)
                    : (XB + (size_t)rows_[it] * IN_DIM + lk);
                __builtin_amdgcn_global_load_lds(
                    (const __attribute__((address_space(1))) void*)sa,
                    (__attribute__((address_space(3))) void*)(As[buf] + dst), 16, 0, 0);
                __builtin_amdgcn_global_load_lds(
                    (const __attribute__((address_space(1))) void*)(gb[it] + kk),
                    (__attribute__((address_space(3))) void*)(Bs[buf] + dst), 16, 0, 0);
            }
        };

        // prologue: fill both buffers; wait only buf0 (its 8 loads are the
        // oldest -> vmcnt(8) drains exactly them when stage(1) is in flight)
        stage(0, 0);
        if (nK > 1) {
            stage(1, 1);
            asm volatile("s_waitcnt vmcnt(8)" ::: "memory");
        } else {
            asm volatile("s_waitcnt vmcnt(0)" ::: "memory");
        }
        asm volatile("s_barrier" ::: "memory");

        for (int ki = 0; ki < nK; ++ki) {
            const int cur = ki & 1;
            const short* Ac = As[cur];
            const short* Bc = Bs[cur];

            // read ALL fragments of buf[cur] up front (24 x ds_read_b128)
            short8 af[2][8], bf[2][4];
#pragma unroll
            for (int c2 = 0; c2 < 2; ++c2) {
                const int xt = ((q + 4 * c2) ^ xq) << 3;
#pragma unroll
                for (int i = 0; i < 8; ++i)
                    af[c2][i] = *(const short8*)(Ac + abase + i * (16 * TK) + xt);
#pragma unroll
                for (int j = 0; j < 4; ++j)
                    bf[c2][j] = *(const short8*)(Bc + bbase + j * (16 * TK) + xt);
            }

            // restage ki+2 into buf[cur]: all waves' reads must be retired
            // first (lgkm drain + barrier), then the 16 loads fly across the
            // MFMA cluster AND the next iteration's, waited 2 barriers later.
            if (ki + 2 < nK) {
                asm volatile("s_waitcnt lgkmcnt(0)" ::: "memory");
                asm volatile("s_barrier" ::: "memory");
                stage(ki + 2, cur);
            }

#pragma unroll
            for (int c2 = 0; c2 < 2; ++c2)
#pragma unroll
                for (int i = 0; i < 8; ++i)
#pragma unroll
                    for (int j = 0; j < 4; ++j)
                        acc[i][j] = __builtin_amdgcn_mfma_f32_16x16x32_bf16(af[c2][i], bf[c2][j], acc[i][j], 0, 0, 0);

            // end-of-step: wait ONLY the oldest 8 loads (stage ki+1) when a
            // younger stage is in flight; full drain otherwise. lgkmcnt(0)
            // included so no wave can cross with ds_reads still in flight
            // (guards the next restage/m-tile; ~free, reads long retired).
            if (ki + 2 < nK)
                asm volatile("s_waitcnt vmcnt(8) lgkmcnt(0)" ::: "memory");
            else
                asm volatile("s_waitcnt vmcnt(0) lgkmcnt(0)" ::: "memory");
            asm volatile("s_barrier" ::: "memory");
        }

        // epilogue: per wave, cols n0 + wn4*64 .. +63 = one 64-col G-group
        // = all 4 gates of 16 hidden units (interleaved weight layout).
        const int G = blockIdx.x * 4 + wn4;
        const int h = G * 16 + colq;
        const float bi  = bias_g[G * 64 +  0 + colq];
        const float bff = bias_g[G * 64 + 16 + colq];
        const float bc  = bias_g[G * 64 + 32 + colq];
        const float bo  = bias_g[G * 64 + 48 + colq];
#pragma unroll
        for (int i = 0; i < 8; ++i) {
            const int pbase = m0 + wm2 * 128 + i * 16 + q * 4;
#pragma unroll
            for (int r = 0; r < 4; ++r) {
                const int pos = pbase + r;
                if (pos < n_act) {
                    const int row = ridx[pos];
                    const float ig = sigmoidf_(acc[i][0][r] + bi);
                    const float fg = sigmoidf_(acc[i][1][r] + bff);
                    const float cg = tanhf_(acc[i][2][r] + bc);
                    const float og = sigmoidf_(acc[i][3][r] + bo);
                    const size_t ci = (size_t)row * HID + h;
                    const float c = first ? (ig * cg) : (fg * cell[ci] + ig * cg);
                    cell[ci] = c;
                    Sout[(size_t)row * HID + h] = f2bf(og * tanhf_(c));
                }
            }
        }
        // final K-iteration ended with a full-drain barrier, so every wave's
        // LDS reads are retired before any wave's next-m-tile restage;
        // epilogue touches no LDS -> no extra barrier needed here.
    }
}

// Single-m-tile gates (R10 form, split-A, 128^2) — used only inside tail_k.
__device__ __forceinline__ void gates_tile(
    short* As, short* Bs, int tid,
    const short* __restrict__ S, const short* __restrict__ XB,
    const short* __restrict__ B,
    const float* __restrict__ bias_g,
    float* __restrict__ cell, short* __restrict__ Sout,
    const int* __restrict__ ridx, int n_act, int m0, int bx)
{
    const int wave = tid >> 6, lane = tid & 63;
    const int wm = wave & 1, wn = wave >> 1;
    const int colq = lane & 15, q = lane >> 4;
    const int lrow8 = lane >> 3;
    const int lk    = (((lane & 7) ^ lrow8) * 8);
    const int n0 = bx * TN;

    int aoff[4][2], boff[4][2];
#pragma unroll
    for (int i = 0; i < 4; ++i) {
        const int Ra = wm * 64 + i * 16 + colq;
        const int Rb = wn * 64 + i * 16 + colq;
#pragma unroll
        for (int c2 = 0; c2 < 2; ++c2) {
            const int C = q + 4 * c2;
            aoff[i][c2] = Ra * TK + ((C ^ (Ra & 7)) << 3);
            boff[i][c2] = Rb * TK + ((C ^ (Rb & 7)) << 3);
        }
    }

    float4v acc[4][4];
#pragma unroll
    for (int i = 0; i < 4; ++i)
#pragma unroll
        for (int j = 0; j < 4; ++j) acc[i][j] = (float4v)0.f;

    const short* gaS[4];
    const short* gaX[4];
    const short* gb[4];
#pragma unroll
    for (int it = 0; it < 4; ++it) {
        const int rr = (wave * 4 + it) * 8;
        const int r0 = ridx[m0 + rr + lrow8];
        gaS[it] = S + (size_t)r0 * HID + lk;
        gaX[it] = XB + (size_t)r0 * IN_DIM + lk;
        gb[it]  = B + (size_t)(n0 + rr + lrow8) * KTOT + lk;
    }

    for (int ki = 0; ki < KTOT / TK; ++ki) {
        const bool fromS = (ki * TK < HID);
#pragma unroll
        for (int it = 0; it < 4; ++it) {
            const int rr = (wave * 4 + it) * 8;
            const short* a0 = fromS ? gaS[it] : gaX[it];
            __builtin_amdgcn_global_load_lds(
                (const __attribute__((address_space(1))) void*)a0,
                (__attribute__((address_space(3))) void*)(As + rr * TK), 16, 0, 0);
            __builtin_amdgcn_global_load_lds(
                (const __attribute__((address_space(1))) void*)gb[it],
                (__attribute__((address_space(3))) void*)(Bs + rr * TK), 16, 0, 0);
            gaS[it] += TK; gb[it] += TK;
        }
        __syncthreads();
#pragma unroll
        for (int c2 = 0; c2 < 2; ++c2) {
            short8 af[4], bf[4];
#pragma unroll
            for (int i = 0; i < 4; ++i) {
                af[i] = *(const short8*)(As + aoff[i][c2]);
                bf[i] = *(const short8*)(Bs + boff[i][c2]);
            }
#pragma unroll
            for (int i = 0; i < 4; ++i)
#pragma unroll
                for (int j = 0; j < 4; ++j)
                    acc[i][j] = __builtin_amdgcn_mfma_f32_16x16x32_bf16(af[i], bf[j], acc[i][j], 0, 0, 0);
        }
        __syncthreads();
    }

    gates_epilogue(acc, m0, bx, wave, lane, 0, bias_g, cell, Sout, ridx, n_act);
    __syncthreads();   // protect As/Bs before caller's next tile
}

// One 128-row midfin tile: mid GEMM (128 cols = W1, K=HID over state only)
// + W2-dot via shuffle+LDS reduction + halt-dot (state·W_halt fp32) +
// halting bookkeeping. red/hbuf alias As (only touched after the k-loop).
__device__ __forceinline__ void midfin_tile(
    short* As, short* Bs, int tid,
    const short* __restrict__ Snew, const short* __restrict__ P,
    const float* __restrict__ bias_p, const float* __restrict__ W_halt,
    const float* __restrict__ W2, const float* __restrict__ b2,
    float* __restrict__ outp, float* __restrict__ p_sum,
    const int* __restrict__ rprev, int* __restrict__ rnext,
    int* __restrict__ cnt, int t, int m0, int n_act)
{
    const int wave = tid >> 6, lane = tid & 63;
    const int wm = wave & 1, wn = wave >> 1;
    const int colq = lane & 15, q = lane >> 4;
    const int lrow8 = lane >> 3;
    const int lk    = (((lane & 7) ^ lrow8) * 8);

    float4v acc[4][4];
#pragma unroll
    for (int i = 0; i < 4; ++i)
#pragma unroll
        for (int j = 0; j < 4; ++j) acc[i][j] = (float4v)0.f;

    const short* ga[4];
    const short* gb[4];
#pragma unroll
    for (int it = 0; it < 4; ++it) {
        const int rr = (wave * 4 + it) * 8;
        ga[it] = Snew + (size_t)rprev[m0 + rr + lrow8] * HID + lk;
        gb[it] = P + (size_t)(rr + lrow8) * HID + lk;
    }
    int aoff[4][2], boff[4][2];
#pragma unroll
    for (int i = 0; i < 4; ++i) {
        const int Ra = wm * 64 + i * 16 + colq;
        const int Rb = wn * 64 + i * 16 + colq;
#pragma unroll
        for (int c2 = 0; c2 < 2; ++c2) {
            const int C = q + 4 * c2;
            aoff[i][c2] = Ra * TK + ((C ^ (Ra & 7)) << 3);
            boff[i][c2] = Rb * TK + ((C ^ (Rb & 7)) << 3);
        }
    }

    for (int k0 = 0; k0 < HID; k0 += TK) {
#pragma unroll
        for (int it = 0; it < 4; ++it) {
            const int rr = (wave * 4 + it) * 8;
            __builtin_amdgcn_global_load_lds(
                (const __attribute__((address_space(1))) void*)ga[it],
                (__attribute__((address_space(3))) void*)(As + rr * TK), 16, 0, 0);
            __builtin_amdgcn_global_load_lds(
                (const __attribute__((address_space(1))) void*)gb[it],
                (__attribute__((address_space(3))) void*)(Bs + rr * TK), 16, 0, 0);
            ga[it] += TK; gb[it] += TK;
        }
        __syncthreads();
#pragma unroll
        for (int c2 = 0; c2 < 2; ++c2) {
            short8 af[4], bf[4];
#pragma unroll
            for (int i = 0; i < 4; ++i) {
                af[i] = *(const short8*)(As + aoff[i][c2]);
                bf[i] = *(const short8*)(Bs + boff[i][c2]);
            }
#pragma unroll
            for (int i = 0; i < 4; ++i)
#pragma unroll
                for (int j = 0; j < 4; ++j)
                    acc[i][j] = __builtin_amdgcn_mfma_f32_16x16x32_bf16(af[i], bf[j], acc[i][j], 0, 0, 0);
        }
        __syncthreads();
    }

    // aliases over As (k-loop done; last barrier above protects)
    float* red  = (float*)As;           // 256 floats: [wn][wm][i][q][r]
    float* hbuf = ((float*)As) + 256;   // 128 floats

    // halt-dot: per row, state · W_halt
    for (int s = 0; s < 32; ++s) {
        const int lr = wave * 32 + s;
        const int row = rprev[m0 + lr];
        const short* Ar = Snew + (size_t)row * HID + lane * 16;
        const short8 v0 = *(const short8*)Ar;
        const short8 v1 = *(const short8*)(Ar + 8);
        const float* Wh = W_halt + lane * 16;
        float hv = 0.f;
#pragma unroll
        for (int e = 0; e < 8; ++e) hv += bf2f(v0[e]) * Wh[e];
#pragma unroll
        for (int e = 0; e < 8; ++e) hv += bf2f(v1[e]) * Wh[8 + e];
#pragma unroll
        for (int o = 32; o > 0; o >>= 1) hv += __shfl_down(hv, o);
        if (lane == 0) hbuf[lr] = hv;
    }

    // relu + W2-dot, reduce over cols
    float pr[4][4];
#pragma unroll
    for (int i = 0; i < 4; ++i)
#pragma unroll
        for (int r = 0; r < 4; ++r) pr[i][r] = 0.f;
#pragma unroll
    for (int j = 0; j < 4; ++j) {
        const int col = wn * 64 + j * 16 + colq;
        const float b = bias_p[col];
        const float w2 = W2[col];
#pragma unroll
        for (int i = 0; i < 4; ++i)
#pragma unroll
            for (int r = 0; r < 4; ++r)
                pr[i][r] += fmaxf(acc[i][j][r] + b, 0.f) * w2;
    }
#pragma unroll
    for (int i = 0; i < 4; ++i)
#pragma unroll
        for (int r = 0; r < 4; ++r) {
            float v = pr[i][r];
            v += __shfl_down(v, 8, 16);
            v += __shfl_down(v, 4, 16);
            v += __shfl_down(v, 2, 16);
            v += __shfl_down(v, 1, 16);
            if (colq == 0)
                red[((((wn * 2) + wm) * 4 + i) * 4 + q) * 4 + r] = v;
        }
    __syncthreads();

    // finalize: one thread per row
    if (tid < TM) {
        const int pos = m0 + tid;
        if (pos < n_act) {
            const int lwm = tid >> 6, i = (tid >> 4) & 3, lq = (tid >> 2) & 3, r = tid & 3;
            const float odot = red[((lwm * 4 + i) * 4 + lq) * 4 + r]
                             + red[(((2 + lwm) * 4 + i) * 4 + lq) * 4 + r];
            const int row = rprev[pos];
            const float ov = sigmoidf_(odot + b2[0]);
            const float h  = sigmoidf_(hbuf[tid] + bias_p[OMID]);
            const float ps = p_sum[row];
            const float pn = ps + h;
            const bool fin = (pn >= 1.f - 1e-3f) || (t == MAX_ITER - 1);
            const float halt = fin ? (1.f - ps) : h;
            outp[row] += ov * halt;
            p_sum[row] = fin ? 1.f : pn;
            if (!fin) {
                const int d = atomicAdd(&cnt[t + 1], 1);
                astore(&rnext[d], row);
            }
        }
    }
    __syncthreads();   // protect As/Bs aliases before caller reuses LDS
}

// Standalone midfin dispatch (steps 0..1).
__global__ __launch_bounds__(256) void midfin_k(
    const short* __restrict__ Snew, const short* __restrict__ P,
    const float* __restrict__ bias_p, const float* __restrict__ W_halt,
    const float* __restrict__ W2, const float* __restrict__ b2,
    float* __restrict__ outp, float* __restrict__ p_sum,
    const int* __restrict__ rprev, int* __restrict__ rnext,
    int* __restrict__ cnt, int t)
{
    __shared__ short As[TM * TK];
    __shared__ short Bs[TN * TK];
    const int n_act = cnt[t];
    for (int tile = blockIdx.x; tile * TM < n_act; tile += gridDim.x)
        midfin_tile(As, Bs, threadIdx.x, Snew, P, bias_p, W_halt, W2, b2,
                    outp, p_sum, rprev, rnext, cnt, t, tile * TM, n_act);
}

// Persistent 64-block tail: midfin(2) + steps 3..7 (gates+midfin) with
// in-kernel barriers. For this data cnt[3]==0 so the generic loop exits
// after midfin(2)+1 barrier; full loop retained for arbitrary data.
__global__ __launch_bounds__(256) void tail_k(
    const short* __restrict__ Wg, const float* __restrict__ bias_g,
    const short* __restrict__ P, const float* __restrict__ bias_p,
    const float* __restrict__ W_halt, const float* __restrict__ W2,
    const float* __restrict__ b2,
    short* __restrict__ S0, short* __restrict__ S1,
    const short* __restrict__ XB,
    float* __restrict__ cell, float* __restrict__ outp,
    float* __restrict__ p_sum,
    int* __restrict__ ridx0, int* __restrict__ ridx1,
    int* __restrict__ cnt, int* __restrict__ bar)
{
    __shared__ short As[TM * TK];
    __shared__ short Bs[TN * TK];
    const int tid = threadIdx.x;
    int phase = 0;
    int t = 2;
    while (true) {
        short* Snew = (t & 1) ? S0 : S1;        // state written by gates(t)
        const int* rprev = (t & 1) ? ridx1 : ridx0;  // L_t
        int* rnext = (t & 1) ? ridx0 : ridx1;        // L_{t+1}
        const int n = aload(&cnt[t]);
        for (int tile = blockIdx.x; tile * TM < n; tile += gridDim.x)
            midfin_tile(As, Bs, tid, Snew, P, bias_p, W_halt, W2, b2,
                        outp, p_sum, rprev, rnext, cnt, t, tile * TM, n);
        if (t == MAX_ITER - 1) break;
        ++phase; gbar(bar, phase, tid);          // publish cnt[t+1], ridx, p_sum
        const int n1 = aload(&cnt[t + 1]);
        if (n1 == 0) break;                      // uniform across blocks
        {
            short* Sot = (t & 1) ? S1 : S0;
            const int ntiles = ((n1 + TM - 1) / TM) * (NGATES / TN);
            for (int e = blockIdx.x; e < ntiles; e += gridDim.x)
                gates_tile(As, Bs, tid, Snew, XB, Wg, bias_g, cell, Sot,
                           rnext, n1, (e >> 5) * TM, e & 31);
        }
        ++phase; gbar(bar, phase, tid);          // publish Sout, cell
        ++t;
    }
}

// one dispatch for all setup: weight packing + XB + bookkeeping init.
// NOTE: S0/S1/cell are deliberately NOT initialized — at t=0 all rows are
// active, so gates(0) writes every state/cell entry before any read.
#define SETUP_XB    (BATCH * IN_DIM)
#define SETUP_WG    (NGATES * KTOT)
#define SETUP_P     (NP * HID)
#define SETUP_TOT   (SETUP_XB + SETUP_WG + SETUP_P)
__global__ __launch_bounds__(256) void setup_k(
    const float* __restrict__ x,
    const float* __restrict__ Whi, const float* __restrict__ Whf,
    const float* __restrict__ Whc, const float* __restrict__ Who,
    const float* __restrict__ Wxi, const float* __restrict__ Wxf,
    const float* __restrict__ Wxc, const float* __restrict__ Wxo,
    const float* __restrict__ bxi, const float* __restrict__ bhi,
    const float* __restrict__ bxf, const float* __restrict__ bhf,
    const float* __restrict__ bxc, const float* __restrict__ bhc,
    const float* __restrict__ bxo, const float* __restrict__ bho,
    const float* __restrict__ W1, const float* __restrict__ b1,
    const float* __restrict__ W_halt, const float* __restrict__ b_halt,
    short* __restrict__ XB,
    float* __restrict__ p_sum,
    int* __restrict__ ridx0, int* __restrict__ ridx1, int* __restrict__ cnt,
    int* __restrict__ bar, float* __restrict__ outp,
    short* __restrict__ Wg, float* __restrict__ bias_g,
    short* __restrict__ P, float* __restrict__ bias_p)
{
    int idx = blockIdx.x * 256 + threadIdx.x;
    if (idx < SETUP_XB) {
        const int row = idx >> 6, k = idx & 63;
        XB[idx] = f2bf(x[idx]);
        if (k == 0) {
            p_sum[row] = 0.f;
            outp[row] = 0.f;
            ridx0[row] = row;   // step 0: identity compaction
            ridx1[row] = 0;     // in-range dummies for padded tile reads
        }
        if (row == 0 && k <= MAX_ITER) cnt[k] = (k == 0) ? BATCH : 0;
        if (row == 1 && k == 0) bar[0] = 0;
        return;
    }
    idx -= SETUP_XB;
    if (idx < SETUP_WG) {
        const int n = idx / KTOT, k = idx - n * KTOT;
        // interleaved layout: n = 64*G + 16*g + q  ->  gate g of hidden h=16*G+q
        const int G = n >> 6, g = (n >> 4) & 3, q = n & 15;
        const int h = G * 16 + q;
        const float* Wh = (g == 0) ? Whi : (g == 1) ? Whf : (g == 2) ? Whc : Who;
        const float* Wx = (g == 0) ? Wxi : (g == 1) ? Wxf : (g == 2) ? Wxc : Wxo;
        const float v = (k < HID) ? Wh[h * HID + k] : Wx[h * IN_DIM + (k - HID)];
        Wg[idx] = f2bf(v);
        if (k == 0) {
            const float* bx = (g == 0) ? bxi : (g == 1) ? bxf : (g == 2) ? bxc : bxo;
            const float* bh = (g == 0) ? bhi : (g == 1) ? bhf : (g == 2) ? bhc : bho;
            bias_g[n] = bx[h] + bh[h];
        }
        return;
    }
    idx -= SETUP_WG;
    if (idx < SETUP_P) {
        const int n = idx >> 10, k = idx & 1023;
        const float v = (n < OMID) ? W1[n * HID + k] : (n == OMID ? W_halt[k] : 0.f);
        P[idx] = f2bf(v);
        if (k == 0) bias_p[n] = (n < OMID) ? b1[n] : (n == OMID ? b_halt[0] : 0.f);
    }
}

extern "C" void kernel_launch(void* const* d_in, const int* in_sizes, int n_in,
                              void* d_out, int out_size, void* d_ws, size_t ws_size,
                              hipStream_t stream) {
    const float* x    = (const float*)d_in[0];
    const float* Wxi  = (const float*)d_in[1];
    const float* bxi  = (const float*)d_in[2];
    const float* Whi  = (const float*)d_in[3];
    const float* bhi  = (const float*)d_in[4];
    const float* Wxf  = (const float*)d_in[5];
    const float* bxf  = (const float*)d_in[6];
    const float* Whf  = (const float*)d_in[7];
    const float* bhf  = (const float*)d_in[8];
    const float* Wxc  = (const float*)d_in[9];
    const float* bxc  = (const float*)d_in[10];
    const float* Whc  = (const float*)d_in[11];
    const float* bhc  = (const float*)d_in[12];
    const float* Wxo  = (const float*)d_in[13];
    const float* bxo  = (const float*)d_in[14];
    const float* Who  = (const float*)d_in[15];
    const float* bho  = (const float*)d_in[16];
    const float* W_halt = (const float*)d_in[17];
    const float* b_halt = (const float*)d_in[18];
    const float* W1   = (const float*)d_in[19];
    const float* b1   = (const float*)d_in[20];
    const float* W2   = (const float*)d_in[21];
    const float* b2   = (const float*)d_in[22];

    char* p = (char*)d_ws;
    auto carve = [&](size_t bytes) { char* r = p; p += (bytes + 255) & ~(size_t)255; return r; };
    short* S0     = (short*)carve((size_t)BATCH * HID * 2);
    short* S1     = (short*)carve((size_t)BATCH * HID * 2);
    short* XB     = (short*)carve((size_t)BATCH * IN_DIM * 2);
    short* Wg     = (short*)carve((size_t)NGATES * KTOT * 2);
    float* bias_g = (float*)carve((size_t)NGATES * 4);
    short* P      = (short*)carve((size_t)NP * HID * 2);
    float* bias_p = (float*)carve((size_t)NP * 4);
    float* cell   = (float*)carve((size_t)BATCH * HID * 4);
    float* p_sum  = (float*)carve((size_t)BATCH * 4);
    int*   ridx0  = (int*)carve((size_t)BATCH * 4);
    int*   ridx1  = (int*)carve((size_t)BATCH * 4);
    int*   cnt    = (int*)carve((size_t)(MAX_ITER + 1) * 4);
    int*   bar    = (int*)carve(256);
    float* outp   = (float*)d_out;

    setup_k<<<(SETUP_TOT + 255) / 256, 256, 0, stream>>>(
        x, Whi, Whf, Whc, Who, Wxi, Wxf, Wxc, Wxo,
        bxi, bhi, bxf, bhf, bxc, bhc, bxo, bho,
        W1, b1, W_halt, b_halt,
        XB, p_sum, ridx0, ridx1, cnt, bar, outp,
        Wg, bias_g, P, bias_p);

    // t=0: state==0 -> x-part only (1 k-iter from XB), cell write-only
    gates_k<<<dim3(NGATES / GTN, 16), 512, 0, stream>>>(
        S0, XB, Wg + HID, bias_g, 1, 0, 1, cell, S1, ridx0, cnt, 0);
    midfin_k<<<64, 256, 0, stream>>>(
        S1, P, bias_p, W_halt, W2, b2, outp, p_sum, ridx0, ridx1, cnt, 0);
    // t=1: full batch (32 m-tiles of 256 -> 2 per y-block)
    gates_k<<<dim3(NGATES / GTN, 16), 512, 0, stream>>>(
        S1, XB, Wg, bias_g, KTOT / TK, HID, 0, cell, S0, ridx1, cnt, 1);
    midfin_k<<<64, 256, 0, stream>>>(
        S0, P, bias_p, W_halt, W2, b2, outp, p_sum, ridx1, ridx0, cnt, 1);
    // t=2: ~half batch (16 m-tiles -> 1 per y-block)
    gates_k<<<dim3(NGATES / GTN, 16), 512, 0, stream>>>(
        S0, XB, Wg, bias_g, KTOT / TK, HID, 0, cell, S1, ridx0, cnt, 2);
    // midfin(2) + steps 3..7 in one persistent 64-block kernel
    tail_k<<<TAILB, 256, 0, stream>>>(
        Wg, bias_g, P, bias_p, W_halt, W2, b2,
        S0, S1, XB, cell, outp, p_sum, ridx0, ridx1, cnt, bar);
}

// Round 4
// 477.292 us; speedup vs baseline: 1.0958x; 1.0958x over previous
//
#include <hip/hip_runtime.h>
#include <hip/hip_bf16.h>

#define BATCH 8192
#define IN_DIM 64
#define HID 1024
#define KTOT 1088   // HID + IN_DIM (fused K; weights laid out [n][KTOT])
#define NGATES 4096 // 4*HID, column c = 64*G + 16*g + q -> gate g of h=16*G+q
#define OMID 128
#define NP 256      // packed P rows (W1 0..127, W_halt 128, zeros)
#define MAX_ITER 8

#define TM 128
#define TN 128
#define TK 64
#define GTM 256     // gates_k m-tile
#define GTN 256     // gates_k n-tile
#define TAILB 64    // tail_k blocks: few enough that a device barrier is cheap

typedef __attribute__((ext_vector_type(8))) short short8;
typedef __attribute__((ext_vector_type(4))) float float4v;

__device__ __forceinline__ float bf2f(short s) {
    union { float f; unsigned u; } v; v.u = ((unsigned)(unsigned short)s) << 16; return v.f;
}
__device__ __forceinline__ short f2bf(float f) {
    union { float f; unsigned u; } v; v.f = f;
    unsigned r = v.u + 0x7fff + ((v.u >> 16) & 1);  // round-to-nearest-even
    return (short)(r >> 16);
}
__device__ __forceinline__ float sigmoidf_(float x) {
    float xc = fminf(fmaxf(x, -30.f), 30.f);
    return 1.f / (1.f + __expf(-xc));
}
__device__ __forceinline__ float tanhf_(float x) {
    float xc = fminf(fmaxf(x, -15.f), 15.f);
    float e = __expf(2.f * xc);
    return (e - 1.f) / (e + 1.f);
}
__device__ __forceinline__ int aload(const int* p) {
    return __hip_atomic_load((int*)p, __ATOMIC_RELAXED, __HIP_MEMORY_SCOPE_AGENT);
}
__device__ __forceinline__ void astore(int* p, int v) {
    __hip_atomic_store(p, v, __ATOMIC_RELAXED, __HIP_MEMORY_SCOPE_AGENT);
}

// 64-block generation barrier (R8-verified; R5/R7/R11: ANY wider barrier
// pays 50-100us in cross-XCD L2 invalidate traffic). RELAXED polling by one
// lane per block with s_sleep; fences only at the crossing points.
__device__ __forceinline__ void gbar(int* bar, int phase, int tid) {
    __syncthreads();
    if (tid == 0) {
        __threadfence();
        __hip_atomic_fetch_add(bar, 1, __ATOMIC_ACQ_REL, __HIP_MEMORY_SCOPE_AGENT);
        while (aload(bar) < TAILB * phase)
            __builtin_amdgcn_s_sleep(8);
        __threadfence();
    }
    __syncthreads();
}

// Shared epilogue: fused LSTM cell update for one 128-row m-tile's
// accumulators (used by the 128^2 gates_tile inside tail_k).
// first=1 (t==0): cell is write-only (c = i*cg == f*0 + i*cg bit-exactly),
// so cell never needs zero-init and t=0 skips the 33.6MB cell read.
__device__ __forceinline__ void gates_epilogue(
    const float4v (&acc)[4][4], int m0, int bx, int wave, int lane, int first,
    const float* __restrict__ bias_g, float* __restrict__ cell,
    short* __restrict__ Sout, const int* __restrict__ ridx, int n_act)
{
    const int wm = wave & 1, wn = wave >> 1;
    const int colq = lane & 15, q = lane >> 4;
    const int G = bx * 2 + wn;   // 64-col group = 16 hidden units
    const int h = G * 16 + colq;
    const float bi  = bias_g[G * 64 +  0 + colq];
    const float bff = bias_g[G * 64 + 16 + colq];
    const float bc  = bias_g[G * 64 + 32 + colq];
    const float bo  = bias_g[G * 64 + 48 + colq];
#pragma unroll
    for (int i = 0; i < 4; ++i) {
        const int pbase = m0 + wm * 64 + i * 16 + q * 4;
#pragma unroll
        for (int r = 0; r < 4; ++r) {
            const int pos = pbase + r;
            if (pos < n_act) {
                const int row = ridx[pos];
                const float ig = sigmoidf_(acc[i][0][r] + bi);
                const float fg = sigmoidf_(acc[i][1][r] + bff);
                const float cg = tanhf_(acc[i][2][r] + bc);
                const float og = sigmoidf_(acc[i][3][r] + bo);
                const size_t ci = (size_t)row * HID + h;
                const float c = first ? (ig * cg) : (fg * cell[ci] + ig * cg);
                cell[ci] = c;
                Sout[(size_t)row * HID + h] = f2bf(og * tanhf_(c));
            }
        }
    }
}

// Gates GEMM, R16 structure: 256x256 tile, 8 waves (2M x 4N), BK=64,
// double-buffered LDS with DEFERRED-WAIT pipeline. R15 post-mortem:
// hoisting all fragments + full lgkm drain before MFMAs caused spill
// (+17MB scratch traffic) and killed the compiler's ds_read->MFMA
// interleave -> 141us. R14's syncthreads variant (117us) drained the
// just-issued stage every K-step (depth-1 pipeline, ~8300cyc/K-step vs
// ~2400 MFMA floor). R16: compute body identical to R14 (compiler
// schedules ds_reads inline with MFMAs); per iteration the schedule is
//   compute(cur) -> lgkmcnt(0)+bar (reads retired, ~free)
//   -> stage(ki+2 -> cur) -> vmcnt(16) (wait ONLY stage(ki+1); ki+2's
//   16 loads stay in flight) + bar.
// Each stage is issued a FULL iteration before its data is consumed, so
// even HBM latency (~900cyc) hides under the ~2500cyc compute. asm
// "memory" ordering pins the stage issue placement (R14 had nothing
// preventing the compiler from sinking the loads to the barrier).
// XCD-RECTANGLE SWIZZLE: dispatch is round-robin (lin&7 = XCD); with
// the natural map every XCD streams ALL 32 A-panels (16.8MB >> 4MB L2,
// FETCH 95MB = structural refetch). Remap each XCD to an 8x-by-4y
// rectangle: per-XCD unique panels = 8 B + 4*2 A (~8.9MB, ~576KB per
// K-step window) -> A staging becomes L2-resident.
// SPLIT A LAYOUT kept (S + XB, final K-chunk from XB, uniform branch).
// LDS XOR swizzle kept (R2: 0 conflicts).
__global__ __launch_bounds__(512, 1) void gates_k(
    const short* __restrict__ S, const short* __restrict__ XB,
    const short* __restrict__ B,
    const float* __restrict__ bias_g, int nK, int hidK, int first,
    float* __restrict__ cell, short* __restrict__ Sout,
    const int* __restrict__ ridx, const int* __restrict__ cnt, int t)
{
    __shared__ short As[2][GTM * TK];   // 2 x 32 KiB
    __shared__ short Bs[2][GTN * TK];   // 2 x 32 KiB
    const int n_act = cnt[t];
    const int tid  = threadIdx.x;
    const int wave = tid >> 6, lane = tid & 63;
    const int wm2 = wave >> 2, wn4 = wave & 3;   // wave -> 128-row half x 64-col quarter
    const int colq = lane & 15, q = lane >> 4;
    const int lrow8 = lane >> 3;
    const int lk    = (((lane & 7) ^ lrow8) * 8);   // pre-swizzled source offset
    const int xq = colq & 7;
    const int abase = (wm2 * 128 + colq) * TK;   // shorts
    const int bbase = (wn4 * 64  + colq) * TK;   // shorts

    // XCD-rectangle swizzle (grid is 16x16 for all gates_k launches).
    int bx, byS;
    {
        const int lin  = (int)blockIdx.x + 16 * (int)blockIdx.y;  // hw order
        const int xcd  = lin & 7;          // round-robin XCD assignment
        const int slot = lin >> 3;         // 0..31 within this XCD
        bx  = (xcd & 1) * 8 + (slot & 7);  // 8 consecutive x per XCD
        byS = (xcd >> 1) * 4 + (slot >> 3);// 4 consecutive y per XCD
    }
    const int n0 = bx * GTN;

    for (int by = byS; by * GTM < n_act; by += 16) {
        const int m0 = by * GTM;

        // per-wave staged rows: wave*32 + it*8 + lrow8 (A and B share the map)
        int rows_[4];
        const short* gb[4];
#pragma unroll
        for (int it = 0; it < 4; ++it) {
            const int rr = wave * 32 + it * 8 + lrow8;
            rows_[it] = ridx[m0 + rr];
            gb[it] = B + (size_t)(n0 + rr) * KTOT + lk;
        }

        float4v acc[8][4];
#pragma unroll
        for (int i = 0; i < 8; ++i)
#pragma unroll
            for (int j = 0; j < 4; ++j) acc[i][j] = (float4v)0.f;

        auto stage = [&](int ki, int buf) {
            const int kk = ki * TK;
            const bool fromS = (kk < hidK);   // kernel-uniform branch
#pragma unroll
            for (int it = 0; it < 4; ++it) {
                const int dst = (wave * 32 + it * 8) * TK;
                const short* sa = fromS
                    ? (S  + (size_t)rows_[it] * HID    + kk + lk)
                    : (XB + (size_t)rows_[it] * IN_DIM + lk);
                __builtin_amdgcn_global_load_lds(
                    (const __attribute__((address_space(1))) void*)sa,
                    (__attribute__((address_space(3))) void*)(As[buf] + dst), 16, 0, 0);
                __builtin_amdgcn_global_load_lds(
                    (const __attribute__((address_space(1))) void*)(gb[it] + kk),
                    (__attribute__((address_space(3))) void*)(Bs[buf] + dst), 16, 0, 0);
            }
        };

        // prologue: fill both buffers, wait only buf0 (oldest 16 of 32).
        stage(0, 0);
        if (nK > 1) {
            stage(1, 1);
            asm volatile("s_waitcnt vmcnt(16)" ::: "memory");
        } else {
            asm volatile("s_waitcnt vmcnt(0)" ::: "memory");
        }
        asm volatile("s_barrier" ::: "memory");

        for (int ki = 0; ki < nK; ++ki) {
            const int cur = ki & 1;
            const short* Ac = As[cur];
            const short* Bc = Bs[cur];
            // compute: ds_reads inline, compiler interleaves with MFMAs
            // via fine-grained lgkmcnt (R14-verified form, 104 VGPR).
#pragma unroll
            for (int c2 = 0; c2 < 2; ++c2) {
                const int xt = ((q + 4 * c2) ^ xq) << 3;
                short8 af[8], bf[4];
#pragma unroll
                for (int i = 0; i < 8; ++i)
                    af[i] = *(const short8*)(Ac + abase + i * (16 * TK) + xt);
#pragma unroll
                for (int j = 0; j < 4; ++j)
                    bf[j] = *(const short8*)(Bc + bbase + j * (16 * TK) + xt);
#pragma unroll
                for (int i = 0; i < 8; ++i)
#pragma unroll
                    for (int j = 0; j < 4; ++j)
                        acc[i][j] = __builtin_amdgcn_mfma_f32_16x16x32_bf16(af[i], bf[j], acc[i][j], 0, 0, 0);
            }
            // this wave's ds_reads of buf[cur] all retired (MFMAs consumed
            // them; lgkmcnt(0) is ~free) -> barrier makes it collective.
            asm volatile("s_waitcnt lgkmcnt(0)" ::: "memory");
            asm volatile("s_barrier" ::: "memory");
            if (ki + 2 < nK) {
                stage(ki + 2, cur);   // refill the buffer just consumed
                // wait ONLY the oldest 16 (stage ki+1); ki+2's stay in flight
                asm volatile("s_waitcnt vmcnt(16)" ::: "memory");
                asm volatile("s_barrier" ::: "memory");
            } else if (ki + 1 < nK) {
                asm volatile("s_waitcnt vmcnt(0)" ::: "memory");
                asm volatile("s_barrier" ::: "memory");
            }
            // last iteration: lgkm+bar above already protects the next
            // m-tile's stage(0) and the epilogue (which touches no LDS).
        }

        // epilogue: per wave, cols n0 + wn4*64 .. +63 = one 64-col G-group
        // = all 4 gates of 16 hidden units (interleaved weight layout).
        const int G = bx * 4 + wn4;
        const int h = G * 16 + colq;
        const float bi  = bias_g[G * 64 +  0 + colq];
        const float bff = bias_g[G * 64 + 16 + colq];
        const float bc  = bias_g[G * 64 + 32 + colq];
        const float bo  = bias_g[G * 64 + 48 + colq];
#pragma unroll
        for (int i = 0; i < 8; ++i) {
            const int pbase = m0 + wm2 * 128 + i * 16 + q * 4;
#pragma unroll
            for (int r = 0; r < 4; ++r) {
                const int pos = pbase + r;
                if (pos < n_act) {
                    const int row = ridx[pos];
                    const float ig = sigmoidf_(acc[i][0][r] + bi);
                    const float fg = sigmoidf_(acc[i][1][r] + bff);
                    const float cg = tanhf_(acc[i][2][r] + bc);
                    const float og = sigmoidf_(acc[i][3][r] + bo);
                    const size_t ci = (size_t)row * HID + h;
                    const float c = first ? (ig * cg) : (fg * cell[ci] + ig * cg);
                    cell[ci] = c;
                    Sout[(size_t)row * HID + h] = f2bf(og * tanhf_(c));
                }
            }
        }
    }
}

// Single-m-tile gates (R10 form, split-A, 128^2) — used only inside tail_k.
__device__ __forceinline__ void gates_tile(
    short* As, short* Bs, int tid,
    const short* __restrict__ S, const short* __restrict__ XB,
    const short* __restrict__ B,
    const float* __restrict__ bias_g,
    float* __restrict__ cell, short* __restrict__ Sout,
    const int* __restrict__ ridx, int n_act, int m0, int bx)
{
    const int wave = tid >> 6, lane = tid & 63;
    const int wm = wave & 1, wn = wave >> 1;
    const int colq = lane & 15, q = lane >> 4;
    const int lrow8 = lane >> 3;
    const int lk    = (((lane & 7) ^ lrow8) * 8);
    const int n0 = bx * TN;

    int aoff[4][2], boff[4][2];
#pragma unroll
    for (int i = 0; i < 4; ++i) {
        const int Ra = wm * 64 + i * 16 + colq;
        const int Rb = wn * 64 + i * 16 + colq;
#pragma unroll
        for (int c2 = 0; c2 < 2; ++c2) {
            const int C = q + 4 * c2;
            aoff[i][c2] = Ra * TK + ((C ^ (Ra & 7)) << 3);
            boff[i][c2] = Rb * TK + ((C ^ (Rb & 7)) << 3);
        }
    }

    float4v acc[4][4];
#pragma unroll
    for (int i = 0; i < 4; ++i)
#pragma unroll
        for (int j = 0; j < 4; ++j) acc[i][j] = (float4v)0.f;

    const short* gaS[4];
    const short* gaX[4];
    const short* gb[4];
#pragma unroll
    for (int it = 0; it < 4; ++it) {
        const int rr = (wave * 4 + it) * 8;
        const int r0 = ridx[m0 + rr + lrow8];
        gaS[it] = S + (size_t)r0 * HID + lk;
        gaX[it] = XB + (size_t)r0 * IN_DIM + lk;
        gb[it]  = B + (size_t)(n0 + rr + lrow8) * KTOT + lk;
    }

    for (int ki = 0; ki < KTOT / TK; ++ki) {
        const bool fromS = (ki * TK < HID);
#pragma unroll
        for (int it = 0; it < 4; ++it) {
            const int rr = (wave * 4 + it) * 8;
            const short* a0 = fromS ? gaS[it] : gaX[it];
            __builtin_amdgcn_global_load_lds(
                (const __attribute__((address_space(1))) void*)a0,
                (__attribute__((address_space(3))) void*)(As + rr * TK), 16, 0, 0);
            __builtin_amdgcn_global_load_lds(
                (const __attribute__((address_space(1))) void*)gb[it],
                (__attribute__((address_space(3))) void*)(Bs + rr * TK), 16, 0, 0);
            gaS[it] += TK; gb[it] += TK;
        }
        __syncthreads();
#pragma unroll
        for (int c2 = 0; c2 < 2; ++c2) {
            short8 af[4], bf[4];
#pragma unroll
            for (int i = 0; i < 4; ++i) {
                af[i] = *(const short8*)(As + aoff[i][c2]);
                bf[i] = *(const short8*)(Bs + boff[i][c2]);
            }
#pragma unroll
            for (int i = 0; i < 4; ++i)
#pragma unroll
                for (int j = 0; j < 4; ++j)
                    acc[i][j] = __builtin_amdgcn_mfma_f32_16x16x32_bf16(af[i], bf[j], acc[i][j], 0, 0, 0);
        }
        __syncthreads();
    }

    gates_epilogue(acc, m0, bx, wave, lane, 0, bias_g, cell, Sout, ridx, n_act);
    __syncthreads();   // protect As/Bs before caller's next tile
}

// One 128-row midfin tile: mid GEMM (128 cols = W1, K=HID over state only)
// + W2-dot via shuffle+LDS reduction + halt-dot (state·W_halt fp32) +
// halting bookkeeping. red/hbuf alias As (only touched after the k-loop).
__device__ __forceinline__ void midfin_tile(
    short* As, short* Bs, int tid,
    const short* __restrict__ Snew, const short* __restrict__ P,
    const float* __restrict__ bias_p, const float* __restrict__ W_halt,
    const float* __restrict__ W2, const float* __restrict__ b2,
    float* __restrict__ outp, float* __restrict__ p_sum,
    const int* __restrict__ rprev, int* __restrict__ rnext,
    int* __restrict__ cnt, int t, int m0, int n_act)
{
    const int wave = tid >> 6, lane = tid & 63;
    const int wm = wave & 1, wn = wave >> 1;
    const int colq = lane & 15, q = lane >> 4;
    const int lrow8 = lane >> 3;
    const int lk    = (((lane & 7) ^ lrow8) * 8);

    float4v acc[4][4];
#pragma unroll
    for (int i = 0; i < 4; ++i)
#pragma unroll
        for (int j = 0; j < 4; ++j) acc[i][j] = (float4v)0.f;

    const short* ga[4];
    const short* gb[4];
#pragma unroll
    for (int it = 0; it < 4; ++it) {
        const int rr = (wave * 4 + it) * 8;
        ga[it] = Snew + (size_t)rprev[m0 + rr + lrow8] * HID + lk;
        gb[it] = P + (size_t)(rr + lrow8) * HID + lk;
    }
    int aoff[4][2], boff[4][2];
#pragma unroll
    for (int i = 0; i < 4; ++i) {
        const int Ra = wm * 64 + i * 16 + colq;
        const int Rb = wn * 64 + i * 16 + colq;
#pragma unroll
        for (int c2 = 0; c2 < 2; ++c2) {
            const int C = q + 4 * c2;
            aoff[i][c2] = Ra * TK + ((C ^ (Ra & 7)) << 3);
            boff[i][c2] = Rb * TK + ((C ^ (Rb & 7)) << 3);
        }
    }

    for (int k0 = 0; k0 < HID; k0 += TK) {
#pragma unroll
        for (int it = 0; it < 4; ++it) {
            const int rr = (wave * 4 + it) * 8;
            __builtin_amdgcn_global_load_lds(
                (const __attribute__((address_space(1))) void*)ga[it],
                (__attribute__((address_space(3))) void*)(As + rr * TK), 16, 0, 0);
            __builtin_amdgcn_global_load_lds(
                (const __attribute__((address_space(1))) void*)gb[it],
                (__attribute__((address_space(3))) void*)(Bs + rr * TK), 16, 0, 0);
            ga[it] += TK; gb[it] += TK;
        }
        __syncthreads();
#pragma unroll
        for (int c2 = 0; c2 < 2; ++c2) {
            short8 af[4], bf[4];
#pragma unroll
            for (int i = 0; i < 4; ++i) {
                af[i] = *(const short8*)(As + aoff[i][c2]);
                bf[i] = *(const short8*)(Bs + boff[i][c2]);
            }
#pragma unroll
            for (int i = 0; i < 4; ++i)
#pragma unroll
                for (int j = 0; j < 4; ++j)
                    acc[i][j] = __builtin_amdgcn_mfma_f32_16x16x32_bf16(af[i], bf[j], acc[i][j], 0, 0, 0);
        }
        __syncthreads();
    }

    // aliases over As (k-loop done; last barrier above protects)
    float* red  = (float*)As;           // 256 floats: [wn][wm][i][q][r]
    float* hbuf = ((float*)As) + 256;   // 128 floats

    // halt-dot: per row, state · W_halt
    for (int s = 0; s < 32; ++s) {
        const int lr = wave * 32 + s;
        const int row = rprev[m0 + lr];
        const short* Ar = Snew + (size_t)row * HID + lane * 16;
        const short8 v0 = *(const short8*)Ar;
        const short8 v1 = *(const short8*)(Ar + 8);
        const float* Wh = W_halt + lane * 16;
        float hv = 0.f;
#pragma unroll
        for (int e = 0; e < 8; ++e) hv += bf2f(v0[e]) * Wh[e];
#pragma unroll
        for (int e = 0; e < 8; ++e) hv += bf2f(v1[e]) * Wh[8 + e];
#pragma unroll
        for (int o = 32; o > 0; o >>= 1) hv += __shfl_down(hv, o);
        if (lane == 0) hbuf[lr] = hv;
    }

    // relu + W2-dot, reduce over cols
    float pr[4][4];
#pragma unroll
    for (int i = 0; i < 4; ++i)
#pragma unroll
        for (int r = 0; r < 4; ++r) pr[i][r] = 0.f;
#pragma unroll
    for (int j = 0; j < 4; ++j) {
        const int col = wn * 64 + j * 16 + colq;
        const float b = bias_p[col];
        const float w2 = W2[col];
#pragma unroll
        for (int i = 0; i < 4; ++i)
#pragma unroll
            for (int r = 0; r < 4; ++r)
                pr[i][r] += fmaxf(acc[i][j][r] + b, 0.f) * w2;
    }
#pragma unroll
    for (int i = 0; i < 4; ++i)
#pragma unroll
        for (int r = 0; r < 4; ++r) {
            float v = pr[i][r];
            v += __shfl_down(v, 8, 16);
            v += __shfl_down(v, 4, 16);
            v += __shfl_down(v, 2, 16);
            v += __shfl_down(v, 1, 16);
            if (colq == 0)
                red[((((wn * 2) + wm) * 4 + i) * 4 + q) * 4 + r] = v;
        }
    __syncthreads();

    // finalize: one thread per row
    if (tid < TM) {
        const int pos = m0 + tid;
        if (pos < n_act) {
            const int lwm = tid >> 6, i = (tid >> 4) & 3, lq = (tid >> 2) & 3, r = tid & 3;
            const float odot = red[((lwm * 4 + i) * 4 + lq) * 4 + r]
                             + red[(((2 + lwm) * 4 + i) * 4 + lq) * 4 + r];
            const int row = rprev[pos];
            const float ov = sigmoidf_(odot + b2[0]);
            const float h  = sigmoidf_(hbuf[tid] + bias_p[OMID]);
            const float ps = p_sum[row];
            const float pn = ps + h;
            const bool fin = (pn >= 1.f - 1e-3f) || (t == MAX_ITER - 1);
            const float halt = fin ? (1.f - ps) : h;
            outp[row] += ov * halt;
            p_sum[row] = fin ? 1.f : pn;
            if (!fin) {
                const int d = atomicAdd(&cnt[t + 1], 1);
                astore(&rnext[d], row);
            }
        }
    }
    __syncthreads();   // protect As/Bs aliases before caller reuses LDS
}

// Standalone midfin dispatch (steps 0..1).
__global__ __launch_bounds__(256) void midfin_k(
    const short* __restrict__ Snew, const short* __restrict__ P,
    const float* __restrict__ bias_p, const float* __restrict__ W_halt,
    const float* __restrict__ W2, const float* __restrict__ b2,
    float* __restrict__ outp, float* __restrict__ p_sum,
    const int* __restrict__ rprev, int* __restrict__ rnext,
    int* __restrict__ cnt, int t)
{
    __shared__ short As[TM * TK];
    __shared__ short Bs[TN * TK];
    const int n_act = cnt[t];
    for (int tile = blockIdx.x; tile * TM < n_act; tile += gridDim.x)
        midfin_tile(As, Bs, threadIdx.x, Snew, P, bias_p, W_halt, W2, b2,
                    outp, p_sum, rprev, rnext, cnt, t, tile * TM, n_act);
}

// Persistent 64-block tail: midfin(2) + steps 3..7 (gates+midfin) with
// in-kernel barriers. For this data cnt[3]==0 so the generic loop exits
// after midfin(2)+1 barrier; full loop retained for arbitrary data.
__global__ __launch_bounds__(256) void tail_k(
    const short* __restrict__ Wg, const float* __restrict__ bias_g,
    const short* __restrict__ P, const float* __restrict__ bias_p,
    const float* __restrict__ W_halt, const float* __restrict__ W2,
    const float* __restrict__ b2,
    short* __restrict__ S0, short* __restrict__ S1,
    const short* __restrict__ XB,
    float* __restrict__ cell, float* __restrict__ outp,
    float* __restrict__ p_sum,
    int* __restrict__ ridx0, int* __restrict__ ridx1,
    int* __restrict__ cnt, int* __restrict__ bar)
{
    __shared__ short As[TM * TK];
    __shared__ short Bs[TN * TK];
    const int tid = threadIdx.x;
    int phase = 0;
    int t = 2;
    while (true) {
        short* Snew = (t & 1) ? S0 : S1;        // state written by gates(t)
        const int* rprev = (t & 1) ? ridx1 : ridx0;  // L_t
        int* rnext = (t & 1) ? ridx0 : ridx1;        // L_{t+1}
        const int n = aload(&cnt[t]);
        for (int tile = blockIdx.x; tile * TM < n; tile += gridDim.x)
            midfin_tile(As, Bs, tid, Snew, P, bias_p, W_halt, W2, b2,
                        outp, p_sum, rprev, rnext, cnt, t, tile * TM, n);
        if (t == MAX_ITER - 1) break;
        ++phase; gbar(bar, phase, tid);          // publish cnt[t+1], ridx, p_sum
        const int n1 = aload(&cnt[t + 1]);
        if (n1 == 0) break;                      // uniform across blocks
        {
            short* Sot = (t & 1) ? S1 : S0;
            const int ntiles = ((n1 + TM - 1) / TM) * (NGATES / TN);
            for (int e = blockIdx.x; e < ntiles; e += gridDim.x)
                gates_tile(As, Bs, tid, Snew, XB, Wg, bias_g, cell, Sot,
                           rnext, n1, (e >> 5) * TM, e & 31);
        }
        ++phase; gbar(bar, phase, tid);          // publish Sout, cell
        ++t;
    }
}

// one dispatch for all setup: weight packing + XB + bookkeeping init.
// NOTE: S0/S1/cell are deliberately NOT initialized — at t=0 all rows are
// active, so gates(0) writes every state/cell entry before any read.
#define SETUP_XB    (BATCH * IN_DIM)
#define SETUP_WG    (NGATES * KTOT)
#define SETUP_P     (NP * HID)
#define SETUP_TOT   (SETUP_XB + SETUP_WG + SETUP_P)
__global__ __launch_bounds__(256) void setup_k(
    const float* __restrict__ x,
    const float* __restrict__ Whi, const float* __restrict__ Whf,
    const float* __restrict__ Whc, const float* __restrict__ Who,
    const float* __restrict__ Wxi, const float* __restrict__ Wxf,
    const float* __restrict__ Wxc, const float* __restrict__ Wxo,
    const float* __restrict__ bxi, const float* __restrict__ bhi,
    const float* __restrict__ bxf, const float* __restrict__ bhf,
    const float* __restrict__ bxc, const float* __restrict__ bhc,
    const float* __restrict__ bxo, const float* __restrict__ bho,
    const float* __restrict__ W1, const float* __restrict__ b1,
    const float* __restrict__ W_halt, const float* __restrict__ b_halt,
    short* __restrict__ XB,
    float* __restrict__ p_sum,
    int* __restrict__ ridx0, int* __restrict__ ridx1, int* __restrict__ cnt,
    int* __restrict__ bar, float* __restrict__ outp,
    short* __restrict__ Wg, float* __restrict__ bias_g,
    short* __restrict__ P, float* __restrict__ bias_p)
{
    int idx = blockIdx.x * 256 + threadIdx.x;
    if (idx < SETUP_XB) {
        const int row = idx >> 6, k = idx & 63;
        XB[idx] = f2bf(x[idx]);
        if (k == 0) {
            p_sum[row] = 0.f;
            outp[row] = 0.f;
            ridx0[row] = row;   // step 0: identity compaction
            ridx1[row] = 0;     // in-range dummies for padded tile reads
        }
        if (row == 0 && k <= MAX_ITER) cnt[k] = (k == 0) ? BATCH : 0;
        if (row == 1 && k == 0) bar[0] = 0;
        return;
    }
    idx -= SETUP_XB;
    if (idx < SETUP_WG) {
        const int n = idx / KTOT, k = idx - n * KTOT;
        // interleaved layout: n = 64*G + 16*g + q  ->  gate g of hidden h=16*G+q
        const int G = n >> 6, g = (n >> 4) & 3, q = n & 15;
        const int h = G * 16 + q;
        const float* Wh = (g == 0) ? Whi : (g == 1) ? Whf : (g == 2) ? Whc : Who;
        const float* Wx = (g == 0) ? Wxi : (g == 1) ? Wxf : (g == 2) ? Wxc : Wxo;
        const float v = (k < HID) ? Wh[h * HID + k] : Wx[h * IN_DIM + (k - HID)];
        Wg[idx] = f2bf(v);
        if (k == 0) {
            const float* bx = (g == 0) ? bxi : (g == 1) ? bxf : (g == 2) ? bxc : bxo;
            const float* bh = (g == 0) ? bhi : (g == 1) ? bhf : (g == 2) ? bhc : bho;
            bias_g[n] = bx[h] + bh[h];
        }
        return;
    }
    idx -= SETUP_WG;
    if (idx < SETUP_P) {
        const int n = idx >> 10, k = idx & 1023;
        const float v = (n < OMID) ? W1[n * HID + k] : (n == OMID ? W_halt[k] : 0.f);
        P[idx] = f2bf(v);
        if (k == 0) bias_p[n] = (n < OMID) ? b1[n] : (n == OMID ? b_halt[0] : 0.f);
    }
}

extern "C" void kernel_launch(void* const* d_in, const int* in_sizes, int n_in,
                              void* d_out, int out_size, void* d_ws, size_t ws_size,
                              hipStream_t stream) {
    const float* x    = (const float*)d_in[0];
    const float* Wxi  = (const float*)d_in[1];
    const float* bxi  = (const float*)d_in[2];
    const float* Whi  = (const float*)d_in[3];
    const float* bhi  = (const float*)d_in[4];
    const float* Wxf  = (const float*)d_in[5];
    const float* bxf  = (const float*)d_in[6];
    const float* Whf  = (const float*)d_in[7];
    const float* bhf  = (const float*)d_in[8];
    const float* Wxc  = (const float*)d_in[9];
    const float* bxc  = (const float*)d_in[10];
    const float* Whc  = (const float*)d_in[11];
    const float* bhc  = (const float*)d_in[12];
    const float* Wxo  = (const float*)d_in[13];
    const float* bxo  = (const float*)d_in[14];
    const float* Who  = (const float*)d_in[15];
    const float* bho  = (const float*)d_in[16];
    const float* W_halt = (const float*)d_in[17];
    const float* b_halt = (const float*)d_in[18];
    const float* W1   = (const float*)d_in[19];
    const float* b1   = (const float*)d_in[20];
    const float* W2   = (const float*)d_in[21];
    const float* b2   = (const float*)d_in[22];

    char* p = (char*)d_ws;
    auto carve = [&](size_t bytes) { char* r = p; p += (bytes + 255) & ~(size_t)255; return r; };
    short* S0     = (short*)carve((size_t)BATCH * HID * 2);
    short* S1     = (short*)carve((size_t)BATCH * HID * 2);
    short* XB     = (short*)carve((size_t)BATCH * IN_DIM * 2);
    short* Wg     = (short*)carve((size_t)NGATES * KTOT * 2);
    float* bias_g = (float*)carve((size_t)NGATES * 4);
    short* P      = (short*)carve((size_t)NP * HID * 2);
    float* bias_p = (float*)carve((size_t)NP * 4);
    float* cell   = (float*)carve((size_t)BATCH * HID * 4);
    float* p_sum  = (float*)carve((size_t)BATCH * 4);
    int*   ridx0  = (int*)carve((size_t)BATCH * 4);
    int*   ridx1  = (int*)carve((size_t)BATCH * 4);
    int*   cnt    = (int*)carve((size_t)(MAX_ITER + 1) * 4);
    int*   bar    = (int*)carve(256);
    float* outp   = (float*)d_out;

    setup_k<<<(SETUP_TOT + 255) / 256, 256, 0, stream>>>(
        x, Whi, Whf, Whc, Who, Wxi, Wxf, Wxc, Wxo,
        bxi, bhi, bxf, bhf, bxc, bhc, bxo, bho,
        W1, b1, W_halt, b_halt,
        XB, p_sum, ridx0, ridx1, cnt, bar, outp,
        Wg, bias_g, P, bias_p);

    // t=0: state==0 -> x-part only (1 k-iter from XB), cell write-only
    gates_k<<<dim3(NGATES / GTN, 16), 512, 0, stream>>>(
        S0, XB, Wg + HID, bias_g, 1, 0, 1, cell, S1, ridx0, cnt, 0);
    midfin_k<<<64, 256, 0, stream>>>(
        S1, P, bias_p, W_halt, W2, b2, outp, p_sum, ridx0, ridx1, cnt, 0);
    // t=1: full batch (32 m-tiles of 256 -> 2 per y-block)
    gates_k<<<dim3(NGATES / GTN, 16), 512, 0, stream>>>(
        S1, XB, Wg, bias_g, KTOT / TK, HID, 0, cell, S0, ridx1, cnt, 1);
    midfin_k<<<64, 256, 0, stream>>>(
        S0, P, bias_p, W_halt, W2, b2, outp, p_sum, ridx1, ridx0, cnt, 1);
    // t=2: ~half batch (16 m-tiles -> 1 per y-block)
    gates_k<<<dim3(NGATES / GTN, 16), 512, 0, stream>>>(
        S0, XB, Wg, bias_g, KTOT / TK, HID, 0, cell, S1, ridx0, cnt, 2);
    // midfin(2) + steps 3..7 in one persistent 64-block kernel
    tail_k<<<TAILB, 256, 0, stream>>>(
        Wg, bias_g, P, bias_p, W_halt, W2, b2,
        S0, S1, XB, cell, outp, p_sum, ridx0, ridx1, cnt, bar);
}

// Round 5
// 474.462 us; speedup vs baseline: 1.1023x; 1.0060x over previous
//
#include <hip/hip_runtime.h>
#include <hip/hip_bf16.h>

#define BATCH 8192
#define IN_DIM 64
#define HID 1024
#define KTOT 1088   // HID + IN_DIM (fused K; weights laid out [n][KTOT])
#define NGATES 4096 // 4*HID, column c = 64*G + 16*g + q -> gate g of h=16*G+q
#define OMID 128
#define NP 256      // packed P rows (W1 0..127, W_halt 128, zeros)
#define MAX_ITER 8

#define TM 128
#define TN 128
#define TK 64
#define GTM 256     // gates_k m-tile
#define GTN 256     // gates_k n-tile
#define TAILB 64    // tail_k blocks: few enough that a device barrier is cheap

typedef __attribute__((ext_vector_type(8))) short short8;
typedef __attribute__((ext_vector_type(4))) float float4v;

__device__ __forceinline__ float bf2f(short s) {
    union { float f; unsigned u; } v; v.u = ((unsigned)(unsigned short)s) << 16; return v.f;
}
__device__ __forceinline__ short f2bf(float f) {
    union { float f; unsigned u; } v; v.f = f;
    unsigned r = v.u + 0x7fff + ((v.u >> 16) & 1);  // round-to-nearest-even
    return (short)(r >> 16);
}
__device__ __forceinline__ float sigmoidf_(float x) {
    float xc = fminf(fmaxf(x, -30.f), 30.f);
    return 1.f / (1.f + __expf(-xc));
}
__device__ __forceinline__ float tanhf_(float x) {
    float xc = fminf(fmaxf(x, -15.f), 15.f);
    float e = __expf(2.f * xc);
    return (e - 1.f) / (e + 1.f);
}
__device__ __forceinline__ int aload(const int* p) {
    return __hip_atomic_load((int*)p, __ATOMIC_RELAXED, __HIP_MEMORY_SCOPE_AGENT);
}
__device__ __forceinline__ void astore(int* p, int v) {
    __hip_atomic_store(p, v, __ATOMIC_RELAXED, __HIP_MEMORY_SCOPE_AGENT);
}

// 64-block generation barrier (R8-verified; R5/R7/R11: ANY wider barrier
// pays 50-100us in cross-XCD L2 invalidate traffic). RELAXED polling by one
// lane per block with s_sleep; fences only at the crossing points.
__device__ __forceinline__ void gbar(int* bar, int phase, int tid) {
    __syncthreads();
    if (tid == 0) {
        __threadfence();
        __hip_atomic_fetch_add(bar, 1, __ATOMIC_ACQ_REL, __HIP_MEMORY_SCOPE_AGENT);
        while (aload(bar) < TAILB * phase)
            __builtin_amdgcn_s_sleep(8);
        __threadfence();
    }
    __syncthreads();
}

// Shared epilogue: fused LSTM cell update for one 128-row m-tile's
// accumulators (used by the 128^2 gates_tile inside tail_k).
// first=1 (t==0): cell is write-only (c = i*cg == f*0 + i*cg bit-exactly),
// so cell never needs zero-init and t=0 skips the 33.6MB cell read.
__device__ __forceinline__ void gates_epilogue(
    const float4v (&acc)[4][4], int m0, int bx, int wave, int lane, int first,
    const float* __restrict__ bias_g, float* __restrict__ cell,
    short* __restrict__ Sout, const int* __restrict__ ridx, int n_act)
{
    const int wm = wave & 1, wn = wave >> 1;
    const int colq = lane & 15, q = lane >> 4;
    const int G = bx * 2 + wn;   // 64-col group = 16 hidden units
    const int h = G * 16 + colq;
    const float bi  = bias_g[G * 64 +  0 + colq];
    const float bff = bias_g[G * 64 + 16 + colq];
    const float bc  = bias_g[G * 64 + 32 + colq];
    const float bo  = bias_g[G * 64 + 48 + colq];
#pragma unroll
    for (int i = 0; i < 4; ++i) {
        const int pbase = m0 + wm * 64 + i * 16 + q * 4;
#pragma unroll
        for (int r = 0; r < 4; ++r) {
            const int pos = pbase + r;
            if (pos < n_act) {
                const int row = ridx[pos];
                const float ig = sigmoidf_(acc[i][0][r] + bi);
                const float fg = sigmoidf_(acc[i][1][r] + bff);
                const float cg = tanhf_(acc[i][2][r] + bc);
                const float og = sigmoidf_(acc[i][3][r] + bo);
                const size_t ci = (size_t)row * HID + h;
                const float c = first ? (ig * cg) : (fg * cell[ci] + ig * cg);
                cell[ci] = c;
                Sout[(size_t)row * HID + h] = f2bf(og * tanhf_(c));
            }
        }
    }
}

// Gates GEMM, R17: 256x256 tile, 8 waves (2M x 4N), BK=64, dbuf LDS,
// 4-PHASE-PER-K-TILE FINE INTERLEAVE (guide T3+T4+T5, m201 template:
// 1563 TF vs the 2-phase ~607 TF ceiling we measured at R14/R16).
// R16 accidental experiment (vmcnt(16) was a NO-OP: stage=8 loads/wave)
// proved even zero-wait async staging stays ~600 TF -> not latency-bound;
// m233's diagnosis applies: stage+barrier+drain overhead is ~72% of each
// K-step in the coarse 2-barrier loop and only the fine phase interleave
// amortizes it. Per phase: {ds_reads ; stage-issue ; s_barrier ;
// lgkmcnt(0) ; sched_barrier ; setprio(1) ; 16 MFMA ; setprio(0) ;
// s_barrier}. Staging (2 loads/thread per half-tile, counts DERIVED):
//   g_kt: p0 B0(kt+1) p1 B1(kt+1) p3 A0,A1(kt+2); group-end vmcnt(4)
//   leaves exactly A(kt+2) in flight (every half gets >=4 phases cover).
// Ledger: A(kt) staged 2 groups early, B(kt) 1 group early; overwrite
// targets always past their readers' lgkmcnt(0)+barrier; all predicates
// kernel-uniform. XCD-rectangle swizzle kept (R16: FETCH 95->69 MB).
// SPLIT A LAYOUT kept (S rows + XB tail-tile; uniform fromS branch).
// LDS XOR swizzle kept (0 conflicts).
__global__ __launch_bounds__(512, 1) void gates_k(
    const short* __restrict__ S, const short* __restrict__ XB,
    const short* __restrict__ B,
    const float* __restrict__ bias_g, int nK, int hidK, int first,
    float* __restrict__ cell, short* __restrict__ Sout,
    const int* __restrict__ ridx, const int* __restrict__ cnt, int t)
{
    __shared__ short As[2][GTM * TK];   // 2 x 32 KiB (halves: rows 0-127 / 128-255)
    __shared__ short Bs[2][GTN * TK];   // 2 x 32 KiB
    const int n_act = cnt[t];
    const int tid  = threadIdx.x;
    const int wave = tid >> 6, lane = tid & 63;
    const int wm2 = wave >> 2, wn4 = wave & 3;   // wave -> 128-row half x 64-col quarter
    const int colq = lane & 15, q = lane >> 4;
    const int lrow8 = lane >> 3;
    const int lk    = (((lane & 7) ^ lrow8) * 8);   // pre-swizzled source offset
    const int xq = colq & 7;
    const int abase = (wm2 * 128 + colq) * TK;   // shorts
    const int bbase = (wn4 * 64  + colq) * TK;   // shorts

    // XCD-rectangle swizzle (grid is 16x16 for all gates_k launches).
    int bx, byS;
    {
        const int lin  = (int)blockIdx.x + 16 * (int)blockIdx.y;  // hw order
        const int xcd  = lin & 7;          // round-robin XCD assignment
        const int slot = lin >> 3;         // 0..31 within this XCD
        bx  = (xcd & 1) * 8 + (slot & 7);  // 8 consecutive x per XCD
        byS = (xcd >> 1) * 4 + (slot >> 3);// 4 consecutive y per XCD
    }
    const int n0 = bx * GTN;

    for (int by = byS; by * GTM < n_act; by += 16) {
        const int m0 = by * GTM;

        // per-thread staged rows, half-tile granularity (2 loads/thread each):
        // half h covers tile rows h*128 + wave*16 + l*8 + lrow8, l in {0,1}
        int arow[2][2];
        const short* bptr[2][2];
#pragma unroll
        for (int h = 0; h < 2; ++h)
#pragma unroll
            for (int l = 0; l < 2; ++l) {
                const int rr = h * 128 + wave * 16 + l * 8 + lrow8;
                arow[h][l] = ridx[m0 + rr];
                bptr[h][l] = B + (size_t)(n0 + rr) * KTOT + lk;
            }

        float4v acc[8][4];
#pragma unroll
        for (int i = 0; i < 8; ++i)
#pragma unroll
            for (int j = 0; j < 4; ++j) acc[i][j] = (float4v)0.f;

        auto stageA = [&](int kt, int h) {   // one A half-tile: 2 loads/thread
            const int kk = kt * TK;
            const bool fromS = (kk < hidK);  // kernel-uniform
#pragma unroll
            for (int l = 0; l < 2; ++l) {
                const int dst = (h * 128 + wave * 16 + l * 8) * TK;
                const short* sa = fromS
                    ? (S  + (size_t)arow[h][l] * HID    + kk + lk)
                    : (XB + (size_t)arow[h][l] * IN_DIM + lk);
                __builtin_amdgcn_global_load_lds(
                    (const __attribute__((address_space(1))) void*)sa,
                    (__attribute__((address_space(3))) void*)(As[kt & 1] + dst), 16, 0, 0);
            }
        };
        auto stageB = [&](int kt, int h) {   // one B half-tile: 2 loads/thread
            const int kk = kt * TK;
#pragma unroll
            for (int l = 0; l < 2; ++l) {
                const int dst = (h * 128 + wave * 16 + l * 8) * TK;
                __builtin_amdgcn_global_load_lds(
                    (const __attribute__((address_space(1))) void*)(bptr[h][l] + kk),
                    (__attribute__((address_space(3))) void*)(Bs[kt & 1] + dst), 16, 0, 0);
            }
        };

        // prologue: K-tile 0 fully + A of K-tile 1 (B(1) comes in g0 p0/p1)
        stageA(0, 0); stageA(0, 1); stageB(0, 0); stageB(0, 1);
        if (nK > 1) {
            stageA(1, 0); stageA(1, 1);
            asm volatile("s_waitcnt vmcnt(4)" ::: "memory");  // drain kt0's 8
        } else {
            asm volatile("s_waitcnt vmcnt(0)" ::: "memory");
        }
        asm volatile("s_barrier" ::: "memory");

        for (int kt = 0; kt < nK; ++kt) {
            const short* Ac = As[kt & 1];
            const short* Bc = Bs[kt & 1];
            const int xt0 = (q ^ xq) << 3;
            const int xt1 = ((q + 4) ^ xq) << 3;
            short8 af[8], bf[4];

            // ---- p0: read af(c2=0) x8 + bf(c2=0) j0,1; stage B0(kt+1);
            //          MFMA i0..7 x j0..1, c2=0
#pragma unroll
            for (int i = 0; i < 8; ++i)
                af[i] = *(const short8*)(Ac + abase + i * (16 * TK) + xt0);
            bf[0] = *(const short8*)(Bc + bbase + 0 * (16 * TK) + xt0);
            bf[1] = *(const short8*)(Bc + bbase + 1 * (16 * TK) + xt0);
            if (kt + 1 < nK) stageB(kt + 1, 0);
            asm volatile("s_barrier" ::: "memory");
            asm volatile("s_waitcnt lgkmcnt(0)" ::: "memory");
            __builtin_amdgcn_sched_barrier(0);
            __builtin_amdgcn_s_setprio(1);
#pragma unroll
            for (int i = 0; i < 8; ++i) {
                acc[i][0] = __builtin_amdgcn_mfma_f32_16x16x32_bf16(af[i], bf[0], acc[i][0], 0, 0, 0);
                acc[i][1] = __builtin_amdgcn_mfma_f32_16x16x32_bf16(af[i], bf[1], acc[i][1], 0, 0, 0);
            }
            __builtin_amdgcn_s_setprio(0);
            asm volatile("s_barrier" ::: "memory");

            // ---- p1: read bf(c2=0) j2,3; stage B1(kt+1); MFMA i0..7 x j2..3, c2=0
            bf[2] = *(const short8*)(Bc + bbase + 2 * (16 * TK) + xt0);
            bf[3] = *(const short8*)(Bc + bbase + 3 * (16 * TK) + xt0);
            if (kt + 1 < nK) stageB(kt + 1, 1);
            asm volatile("s_barrier" ::: "memory");
            asm volatile("s_waitcnt lgkmcnt(0)" ::: "memory");
            __builtin_amdgcn_sched_barrier(0);
            __builtin_amdgcn_s_setprio(1);
#pragma unroll
            for (int i = 0; i < 8; ++i) {
                acc[i][2] = __builtin_amdgcn_mfma_f32_16x16x32_bf16(af[i], bf[2], acc[i][2], 0, 0, 0);
                acc[i][3] = __builtin_amdgcn_mfma_f32_16x16x32_bf16(af[i], bf[3], acc[i][3], 0, 0, 0);
            }
            __builtin_amdgcn_s_setprio(0);
            asm volatile("s_barrier" ::: "memory");

            // ---- p2: read af(c2=1) x8 + bf(c2=1) j0,1; MFMA i0..7 x j0..1, c2=1
#pragma unroll
            for (int i = 0; i < 8; ++i)
                af[i] = *(const short8*)(Ac + abase + i * (16 * TK) + xt1);
            bf[0] = *(const short8*)(Bc + bbase + 0 * (16 * TK) + xt1);
            bf[1] = *(const short8*)(Bc + bbase + 1 * (16 * TK) + xt1);
            asm volatile("s_barrier" ::: "memory");
            asm volatile("s_waitcnt lgkmcnt(0)" ::: "memory");
            __builtin_amdgcn_sched_barrier(0);
            __builtin_amdgcn_s_setprio(1);
#pragma unroll
            for (int i = 0; i < 8; ++i) {
                acc[i][0] = __builtin_amdgcn_mfma_f32_16x16x32_bf16(af[i], bf[0], acc[i][0], 0, 0, 0);
                acc[i][1] = __builtin_amdgcn_mfma_f32_16x16x32_bf16(af[i], bf[1], acc[i][1], 0, 0, 0);
            }
            __builtin_amdgcn_s_setprio(0);
            asm volatile("s_barrier" ::: "memory");

            // ---- p3: read bf(c2=1) j2,3; stage A0,A1(kt+2); MFMA i0..7 x j2..3,
            //          c2=1; group-end counted vmcnt
            bf[2] = *(const short8*)(Bc + bbase + 2 * (16 * TK) + xt1);
            bf[3] = *(const short8*)(Bc + bbase + 3 * (16 * TK) + xt1);
            if (kt + 2 < nK) { stageA(kt + 2, 0); stageA(kt + 2, 1); }
            asm volatile("s_barrier" ::: "memory");
            asm volatile("s_waitcnt lgkmcnt(0)" ::: "memory");
            __builtin_amdgcn_sched_barrier(0);
            __builtin_amdgcn_s_setprio(1);
#pragma unroll
            for (int i = 0; i < 8; ++i) {
                acc[i][2] = __builtin_amdgcn_mfma_f32_16x16x32_bf16(af[i], bf[2], acc[i][2], 0, 0, 0);
                acc[i][3] = __builtin_amdgcn_mfma_f32_16x16x32_bf16(af[i], bf[3], acc[i][3], 0, 0, 0);
            }
            __builtin_amdgcn_s_setprio(0);
            // group-end: drain everything except A(kt+2) (4 loads/thread)
            if (kt + 2 < nK)
                asm volatile("s_waitcnt vmcnt(4)" ::: "memory");
            else
                asm volatile("s_waitcnt vmcnt(0)" ::: "memory");
            asm volatile("s_barrier" ::: "memory");
        }

        // epilogue: per wave, cols n0 + wn4*64 .. +63 = one 64-col G-group
        // = all 4 gates of 16 hidden units (interleaved weight layout).
        const int G = bx * 4 + wn4;
        const int h = G * 16 + colq;
        const float bi  = bias_g[G * 64 +  0 + colq];
        const float bff = bias_g[G * 64 + 16 + colq];
        const float bc  = bias_g[G * 64 + 32 + colq];
        const float bo  = bias_g[G * 64 + 48 + colq];
#pragma unroll
        for (int i = 0; i < 8; ++i) {
            const int pbase = m0 + wm2 * 128 + i * 16 + q * 4;
#pragma unroll
            for (int r = 0; r < 4; ++r) {
                const int pos = pbase + r;
                if (pos < n_act) {
                    const int row = ridx[pos];
                    const float ig = sigmoidf_(acc[i][0][r] + bi);
                    const float fg = sigmoidf_(acc[i][1][r] + bff);
                    const float cg = tanhf_(acc[i][2][r] + bc);
                    const float og = sigmoidf_(acc[i][3][r] + bo);
                    const size_t ci = (size_t)row * HID + h;
                    const float c = first ? (ig * cg) : (fg * cell[ci] + ig * cg);
                    cell[ci] = c;
                    Sout[(size_t)row * HID + h] = f2bf(og * tanhf_(c));
                }
            }
        }
        // final group ended with a full-drain barrier; epilogue touches no
        // LDS; next m-tile's prologue stages are safe.
    }
}

// Single-m-tile gates (R10 form, split-A, 128^2) — used only inside tail_k.
__device__ __forceinline__ void gates_tile(
    short* As, short* Bs, int tid,
    const short* __restrict__ S, const short* __restrict__ XB,
    const short* __restrict__ B,
    const float* __restrict__ bias_g,
    float* __restrict__ cell, short* __restrict__ Sout,
    const int* __restrict__ ridx, int n_act, int m0, int bx)
{
    const int wave = tid >> 6, lane = tid & 63;
    const int wm = wave & 1, wn = wave >> 1;
    const int colq = lane & 15, q = lane >> 4;
    const int lrow8 = lane >> 3;
    const int lk    = (((lane & 7) ^ lrow8) * 8);
    const int n0 = bx * TN;

    int aoff[4][2], boff[4][2];
#pragma unroll
    for (int i = 0; i < 4; ++i) {
        const int Ra = wm * 64 + i * 16 + colq;
        const int Rb = wn * 64 + i * 16 + colq;
#pragma unroll
        for (int c2 = 0; c2 < 2; ++c2) {
            const int C = q + 4 * c2;
            aoff[i][c2] = Ra * TK + ((C ^ (Ra & 7)) << 3);
            boff[i][c2] = Rb * TK + ((C ^ (Rb & 7)) << 3);
        }
    }

    float4v acc[4][4];
#pragma unroll
    for (int i = 0; i < 4; ++i)
#pragma unroll
        for (int j = 0; j < 4; ++j) acc[i][j] = (float4v)0.f;

    const short* gaS[4];
    const short* gaX[4];
    const short* gb[4];
#pragma unroll
    for (int it = 0; it < 4; ++it) {
        const int rr = (wave * 4 + it) * 8;
        const int r0 = ridx[m0 + rr + lrow8];
        gaS[it] = S + (size_t)r0 * HID + lk;
        gaX[it] = XB + (size_t)r0 * IN_DIM + lk;
        gb[it]  = B + (size_t)(n0 + rr + lrow8) * KTOT + lk;
    }

    for (int ki = 0; ki < KTOT / TK; ++ki) {
        const bool fromS = (ki * TK < HID);
#pragma unroll
        for (int it = 0; it < 4; ++it) {
            const int rr = (wave * 4 + it) * 8;
            const short* a0 = fromS ? gaS[it] : gaX[it];
            __builtin_amdgcn_global_load_lds(
                (const __attribute__((address_space(1))) void*)a0,
                (__attribute__((address_space(3))) void*)(As + rr * TK), 16, 0, 0);
            __builtin_amdgcn_global_load_lds(
                (const __attribute__((address_space(1))) void*)gb[it],
                (__attribute__((address_space(3))) void*)(Bs + rr * TK), 16, 0, 0);
            gaS[it] += TK; gb[it] += TK;
        }
        __syncthreads();
#pragma unroll
        for (int c2 = 0; c2 < 2; ++c2) {
            short8 af[4], bf[4];
#pragma unroll
            for (int i = 0; i < 4; ++i) {
                af[i] = *(const short8*)(As + aoff[i][c2]);
                bf[i] = *(const short8*)(Bs + boff[i][c2]);
            }
#pragma unroll
            for (int i = 0; i < 4; ++i)
#pragma unroll
                for (int j = 0; j < 4; ++j)
                    acc[i][j] = __builtin_amdgcn_mfma_f32_16x16x32_bf16(af[i], bf[j], acc[i][j], 0, 0, 0);
        }
        __syncthreads();
    }

    gates_epilogue(acc, m0, bx, wave, lane, 0, bias_g, cell, Sout, ridx, n_act);
    __syncthreads();   // protect As/Bs before caller's next tile
}

// One 128-row midfin tile: mid GEMM (128 cols = W1, K=HID over state only)
// + W2-dot via shuffle+LDS reduction + halt-dot (state·W_halt fp32) +
// halting bookkeeping. red/hbuf alias As (only touched after the k-loop).
__device__ __forceinline__ void midfin_tile(
    short* As, short* Bs, int tid,
    const short* __restrict__ Snew, const short* __restrict__ P,
    const float* __restrict__ bias_p, const float* __restrict__ W_halt,
    const float* __restrict__ W2, const float* __restrict__ b2,
    float* __restrict__ outp, float* __restrict__ p_sum,
    const int* __restrict__ rprev, int* __restrict__ rnext,
    int* __restrict__ cnt, int t, int m0, int n_act)
{
    const int wave = tid >> 6, lane = tid & 63;
    const int wm = wave & 1, wn = wave >> 1;
    const int colq = lane & 15, q = lane >> 4;
    const int lrow8 = lane >> 3;
    const int lk    = (((lane & 7) ^ lrow8) * 8);

    float4v acc[4][4];
#pragma unroll
    for (int i = 0; i < 4; ++i)
#pragma unroll
        for (int j = 0; j < 4; ++j) acc[i][j] = (float4v)0.f;

    const short* ga[4];
    const short* gb[4];
#pragma unroll
    for (int it = 0; it < 4; ++it) {
        const int rr = (wave * 4 + it) * 8;
        ga[it] = Snew + (size_t)rprev[m0 + rr + lrow8] * HID + lk;
        gb[it] = P + (size_t)(rr + lrow8) * HID + lk;
    }
    int aoff[4][2], boff[4][2];
#pragma unroll
    for (int i = 0; i < 4; ++i) {
        const int Ra = wm * 64 + i * 16 + colq;
        const int Rb = wn * 64 + i * 16 + colq;
#pragma unroll
        for (int c2 = 0; c2 < 2; ++c2) {
            const int C = q + 4 * c2;
            aoff[i][c2] = Ra * TK + ((C ^ (Ra & 7)) << 3);
            boff[i][c2] = Rb * TK + ((C ^ (Rb & 7)) << 3);
        }
    }

    for (int k0 = 0; k0 < HID; k0 += TK) {
#pragma unroll
        for (int it = 0; it < 4; ++it) {
            const int rr = (wave * 4 + it) * 8;
            __builtin_amdgcn_global_load_lds(
                (const __attribute__((address_space(1))) void*)ga[it],
                (__attribute__((address_space(3))) void*)(As + rr * TK), 16, 0, 0);
            __builtin_amdgcn_global_load_lds(
                (const __attribute__((address_space(1))) void*)gb[it],
                (__attribute__((address_space(3))) void*)(Bs + rr * TK), 16, 0, 0);
            ga[it] += TK; gb[it] += TK;
        }
        __syncthreads();
#pragma unroll
        for (int c2 = 0; c2 < 2; ++c2) {
            short8 af[4], bf[4];
#pragma unroll
            for (int i = 0; i < 4; ++i) {
                af[i] = *(const short8*)(As + aoff[i][c2]);
                bf[i] = *(const short8*)(Bs + boff[i][c2]);
            }
#pragma unroll
            for (int i = 0; i < 4; ++i)
#pragma unroll
                for (int j = 0; j < 4; ++j)
                    acc[i][j] = __builtin_amdgcn_mfma_f32_16x16x32_bf16(af[i], bf[j], acc[i][j], 0, 0, 0);
        }
        __syncthreads();
    }

    // aliases over As (k-loop done; last barrier above protects)
    float* red  = (float*)As;           // 256 floats: [wn][wm][i][q][r]
    float* hbuf = ((float*)As) + 256;   // 128 floats

    // halt-dot: per row, state · W_halt
    for (int s = 0; s < 32; ++s) {
        const int lr = wave * 32 + s;
        const int row = rprev[m0 + lr];
        const short* Ar = Snew + (size_t)row * HID + lane * 16;
        const short8 v0 = *(const short8*)Ar;
        const short8 v1 = *(const short8*)(Ar + 8);
        const float* Wh = W_halt + lane * 16;
        float hv = 0.f;
#pragma unroll
        for (int e = 0; e < 8; ++e) hv += bf2f(v0[e]) * Wh[e];
#pragma unroll
        for (int e = 0; e < 8; ++e) hv += bf2f(v1[e]) * Wh[8 + e];
#pragma unroll
        for (int o = 32; o > 0; o >>= 1) hv += __shfl_down(hv, o);
        if (lane == 0) hbuf[lr] = hv;
    }

    // relu + W2-dot, reduce over cols
    float pr[4][4];
#pragma unroll
    for (int i = 0; i < 4; ++i)
#pragma unroll
        for (int r = 0; r < 4; ++r) pr[i][r] = 0.f;
#pragma unroll
    for (int j = 0; j < 4; ++j) {
        const int col = wn * 64 + j * 16 + colq;
        const float b = bias_p[col];
        const float w2 = W2[col];
#pragma unroll
        for (int i = 0; i < 4; ++i)
#pragma unroll
            for (int r = 0; r < 4; ++r)
                pr[i][r] += fmaxf(acc[i][j][r] + b, 0.f) * w2;
    }
#pragma unroll
    for (int i = 0; i < 4; ++i)
#pragma unroll
        for (int r = 0; r < 4; ++r) {
            float v = pr[i][r];
            v += __shfl_down(v, 8, 16);
            v += __shfl_down(v, 4, 16);
            v += __shfl_down(v, 2, 16);
            v += __shfl_down(v, 1, 16);
            if (colq == 0)
                red[((((wn * 2) + wm) * 4 + i) * 4 + q) * 4 + r] = v;
        }
    __syncthreads();

    // finalize: one thread per row
    if (tid < TM) {
        const int pos = m0 + tid;
        if (pos < n_act) {
            const int lwm = tid >> 6, i = (tid >> 4) & 3, lq = (tid >> 2) & 3, r = tid & 3;
            const float odot = red[((lwm * 4 + i) * 4 + lq) * 4 + r]
                             + red[(((2 + lwm) * 4 + i) * 4 + lq) * 4 + r];
            const int row = rprev[pos];
            const float ov = sigmoidf_(odot + b2[0]);
            const float h  = sigmoidf_(hbuf[tid] + bias_p[OMID]);
            const float ps = p_sum[row];
            const float pn = ps + h;
            const bool fin = (pn >= 1.f - 1e-3f) || (t == MAX_ITER - 1);
            const float halt = fin ? (1.f - ps) : h;
            outp[row] += ov * halt;
            p_sum[row] = fin ? 1.f : pn;
            if (!fin) {
                const int d = atomicAdd(&cnt[t + 1], 1);
                astore(&rnext[d], row);
            }
        }
    }
    __syncthreads();   // protect As/Bs aliases before caller reuses LDS
}

// Standalone midfin dispatch (steps 0..1).
__global__ __launch_bounds__(256) void midfin_k(
    const short* __restrict__ Snew, const short* __restrict__ P,
    const float* __restrict__ bias_p, const float* __restrict__ W_halt,
    const float* __restrict__ W2, const float* __restrict__ b2,
    float* __restrict__ outp, float* __restrict__ p_sum,
    const int* __restrict__ rprev, int* __restrict__ rnext,
    int* __restrict__ cnt, int t)
{
    __shared__ short As[TM * TK];
    __shared__ short Bs[TN * TK];
    const int n_act = cnt[t];
    for (int tile = blockIdx.x; tile * TM < n_act; tile += gridDim.x)
        midfin_tile(As, Bs, threadIdx.x, Snew, P, bias_p, W_halt, W2, b2,
                    outp, p_sum, rprev, rnext, cnt, t, tile * TM, n_act);
}

// Persistent 64-block tail: midfin(2) + steps 3..7 (gates+midfin) with
// in-kernel barriers. For this data cnt[3]==0 so the generic loop exits
// after midfin(2)+1 barrier; full loop retained for arbitrary data.
__global__ __launch_bounds__(256) void tail_k(
    const short* __restrict__ Wg, const float* __restrict__ bias_g,
    const short* __restrict__ P, const float* __restrict__ bias_p,
    const float* __restrict__ W_halt, const float* __restrict__ W2,
    const float* __restrict__ b2,
    short* __restrict__ S0, short* __restrict__ S1,
    const short* __restrict__ XB,
    float* __restrict__ cell, float* __restrict__ outp,
    float* __restrict__ p_sum,
    int* __restrict__ ridx0, int* __restrict__ ridx1,
    int* __restrict__ cnt, int* __restrict__ bar)
{
    __shared__ short As[TM * TK];
    __shared__ short Bs[TN * TK];
    const int tid = threadIdx.x;
    int phase = 0;
    int t = 2;
    while (true) {
        short* Snew = (t & 1) ? S0 : S1;        // state written by gates(t)
        const int* rprev = (t & 1) ? ridx1 : ridx0;  // L_t
        int* rnext = (t & 1) ? ridx0 : ridx1;        // L_{t+1}
        const int n = aload(&cnt[t]);
        for (int tile = blockIdx.x; tile * TM < n; tile += gridDim.x)
            midfin_tile(As, Bs, tid, Snew, P, bias_p, W_halt, W2, b2,
                        outp, p_sum, rprev, rnext, cnt, t, tile * TM, n);
        if (t == MAX_ITER - 1) break;
        ++phase; gbar(bar, phase, tid);          // publish cnt[t+1], ridx, p_sum
        const int n1 = aload(&cnt[t + 1]);
        if (n1 == 0) break;                      // uniform across blocks
        {
            short* Sot = (t & 1) ? S1 : S0;
            const int ntiles = ((n1 + TM - 1) / TM) * (NGATES / TN);
            for (int e = blockIdx.x; e < ntiles; e += gridDim.x)
                gates_tile(As, Bs, tid, Snew, XB, Wg, bias_g, cell, Sot,
                           rnext, n1, (e >> 5) * TM, e & 31);
        }
        ++phase; gbar(bar, phase, tid);          // publish Sout, cell
        ++t;
    }
}

// one dispatch for all setup: weight packing + XB + bookkeeping init.
// NOTE: S0/S1/cell are deliberately NOT initialized — at t=0 all rows are
// active, so gates(0) writes every state/cell entry before any read.
#define SETUP_XB    (BATCH * IN_DIM)
#define SETUP_WG    (NGATES * KTOT)
#define SETUP_P     (NP * HID)
#define SETUP_TOT   (SETUP_XB + SETUP_WG + SETUP_P)
__global__ __launch_bounds__(256) void setup_k(
    const float* __restrict__ x,
    const float* __restrict__ Whi, const float* __restrict__ Whf,
    const float* __restrict__ Whc, const float* __restrict__ Who,
    const float* __restrict__ Wxi, const float* __restrict__ Wxf,
    const float* __restrict__ Wxc, const float* __restrict__ Wxo,
    const float* __restrict__ bxi, const float* __restrict__ bhi,
    const float* __restrict__ bxf, const float* __restrict__ bhf,
    const float* __restrict__ bxc, const float* __restrict__ bhc,
    const float* __restrict__ bxo, const float* __restrict__ bho,
    const float* __restrict__ W1, const float* __restrict__ b1,
    const float* __restrict__ W_halt, const float* __restrict__ b_halt,
    short* __restrict__ XB,
    float* __restrict__ p_sum,
    int* __restrict__ ridx0, int* __restrict__ ridx1, int* __restrict__ cnt,
    int* __restrict__ bar, float* __restrict__ outp,
    short* __restrict__ Wg, float* __restrict__ bias_g,
    short* __restrict__ P, float* __restrict__ bias_p)
{
    int idx = blockIdx.x * 256 + threadIdx.x;
    if (idx < SETUP_XB) {
        const int row = idx >> 6, k = idx & 63;
        XB[idx] = f2bf(x[idx]);
        if (k == 0) {
            p_sum[row] = 0.f;
            outp[row] = 0.f;
            ridx0[row] = row;   // step 0: identity compaction
            ridx1[row] = 0;     // in-range dummies for padded tile reads
        }
        if (row == 0 && k <= MAX_ITER) cnt[k] = (k == 0) ? BATCH : 0;
        if (row == 1 && k == 0) bar[0] = 0;
        return;
    }
    idx -= SETUP_XB;
    if (idx < SETUP_WG) {
        const int n = idx / KTOT, k = idx - n * KTOT;
        // interleaved layout: n = 64*G + 16*g + q  ->  gate g of hidden h=16*G+q
        const int G = n >> 6, g = (n >> 4) & 3, q = n & 15;
        const int h = G * 16 + q;
        const float* Wh = (g == 0) ? Whi : (g == 1) ? Whf : (g == 2) ? Whc : Who;
        const float* Wx = (g == 0) ? Wxi : (g == 1) ? Wxf : (g == 2) ? Wxc : Wxo;
        const float v = (k < HID) ? Wh[h * HID + k] : Wx[h * IN_DIM + (k - HID)];
        Wg[idx] = f2bf(v);
        if (k == 0) {
            const float* bx = (g == 0) ? bxi : (g == 1) ? bxf : (g == 2) ? bxc : bxo;
            const float* bh = (g == 0) ? bhi : (g == 1) ? bhf : (g == 2) ? bhc : bho;
            bias_g[n] = bx[h] + bh[h];
        }
        return;
    }
    idx -= SETUP_WG;
    if (idx < SETUP_P) {
        const int n = idx >> 10, k = idx & 1023;
        const float v = (n < OMID) ? W1[n * HID + k] : (n == OMID ? W_halt[k] : 0.f);
        P[idx] = f2bf(v);
        if (k == 0) bias_p[n] = (n < OMID) ? b1[n] : (n == OMID ? b_halt[0] : 0.f);
    }
}

extern "C" void kernel_launch(void* const* d_in, const int* in_sizes, int n_in,
                              void* d_out, int out_size, void* d_ws, size_t ws_size,
                              hipStream_t stream) {
    const float* x    = (const float*)d_in[0];
    const float* Wxi  = (const float*)d_in[1];
    const float* bxi  = (const float*)d_in[2];
    const float* Whi  = (const float*)d_in[3];
    const float* bhi  = (const float*)d_in[4];
    const float* Wxf  = (const float*)d_in[5];
    const float* bxf  = (const float*)d_in[6];
    const float* Whf  = (const float*)d_in[7];
    const float* bhf  = (const float*)d_in[8];
    const float* Wxc  = (const float*)d_in[9];
    const float* bxc  = (const float*)d_in[10];
    const float* Whc  = (const float*)d_in[11];
    const float* bhc  = (const float*)d_in[12];
    const float* Wxo  = (const float*)d_in[13];
    const float* bxo  = (const float*)d_in[14];
    const float* Who  = (const float*)d_in[15];
    const float* bho  = (const float*)d_in[16];
    const float* W_halt = (const float*)d_in[17];
    const float* b_halt = (const float*)d_in[18];
    const float* W1   = (const float*)d_in[19];
    const float* b1   = (const float*)d_in[20];
    const float* W2   = (const float*)d_in[21];
    const float* b2   = (const float*)d_in[22];

    char* p = (char*)d_ws;
    auto carve = [&](size_t bytes) { char* r = p; p += (bytes + 255) & ~(size_t)255; return r; };
    short* S0     = (short*)carve((size_t)BATCH * HID * 2);
    short* S1     = (short*)carve((size_t)BATCH * HID * 2);
    short* XB     = (short*)carve((size_t)BATCH * IN_DIM * 2);
    short* Wg     = (short*)carve((size_t)NGATES * KTOT * 2);
    float* bias_g = (float*)carve((size_t)NGATES * 4);
    short* P      = (short*)carve((size_t)NP * HID * 2);
    float* bias_p = (float*)carve((size_t)NP * 4);
    float* cell   = (float*)carve((size_t)BATCH * HID * 4);
    float* p_sum  = (float*)carve((size_t)BATCH * 4);
    int*   ridx0  = (int*)carve((size_t)BATCH * 4);
    int*   ridx1  = (int*)carve((size_t)BATCH * 4);
    int*   cnt    = (int*)carve((size_t)(MAX_ITER + 1) * 4);
    int*   bar    = (int*)carve(256);
    float* outp   = (float*)d_out;

    setup_k<<<(SETUP_TOT + 255) / 256, 256, 0, stream>>>(
        x, Whi, Whf, Whc, Who, Wxi, Wxf, Wxc, Wxo,
        bxi, bhi, bxf, bhf, bxc, bhc, bxo, bho,
        W1, b1, W_halt, b_halt,
        XB, p_sum, ridx0, ridx1, cnt, bar, outp,
        Wg, bias_g, P, bias_p);

    // t=0: state==0 -> x-part only (1 k-iter from XB), cell write-only
    gates_k<<<dim3(16, 16), 512, 0, stream>>>(
        S0, XB, Wg + HID, bias_g, 1, 0, 1, cell, S1, ridx0, cnt, 0);
    midfin_k<<<64, 256, 0, stream>>>(
        S1, P, bias_p, W_halt, W2, b2, outp, p_sum, ridx0, ridx1, cnt, 0);
    // t=1: full batch (32 m-tiles of 256 -> 2 per y-block)
    gates_k<<<dim3(16, 16), 512, 0, stream>>>(
        S1, XB, Wg, bias_g, KTOT / TK, HID, 0, cell, S0, ridx1, cnt, 1);
    midfin_k<<<64, 256, 0, stream>>>(
        S0, P, bias_p, W_halt, W2, b2, outp, p_sum, ridx1, ridx0, cnt, 1);
    // t=2: ~half batch (16 m-tiles -> 1 per y-block)
    gates_k<<<dim3(16, 16), 512, 0, stream>>>(
        S0, XB, Wg, bias_g, KTOT / TK, HID, 0, cell, S1, ridx0, cnt, 2);
    // midfin(2) + steps 3..7 in one persistent 64-block kernel
    tail_k<<<TAILB, 256, 0, stream>>>(
        Wg, bias_g, P, bias_p, W_halt, W2, b2,
        S0, S1, XB, cell, outp, p_sum, ridx0, ridx1, cnt, bar);
}

// Round 6
// 445.944 us; speedup vs baseline: 1.1728x; 1.0639x over previous
//
#include <hip/hip_runtime.h>
#include <hip/hip_bf16.h>

#define BATCH 8192
#define IN_DIM 64
#define HID 1024
#define KTOT 1088   // HID + IN_DIM (fused K; weights laid out [n][KTOT])
#define NGATES 4096 // 4*HID, column c = 64*G + 16*g + q -> gate g of h=16*G+q
#define OMID 128
#define NP 256      // packed P rows (W1 0..127, W_halt 128, zeros)
#define MAX_ITER 8

#define TM 128
#define TN 128
#define TK 64
#define TMF 32      // midfin m-tile (R18: 32 rows -> 256 tiles, full machine)
#define GTM 256     // gates_k m-tile
#define GTN 256     // gates_k n-tile
#define TAILB 64    // tail_k blocks: few enough that a device barrier is cheap

typedef __attribute__((ext_vector_type(8))) short short8;
typedef __attribute__((ext_vector_type(4))) float float4v;

__device__ __forceinline__ float bf2f(short s) {
    union { float f; unsigned u; } v; v.u = ((unsigned)(unsigned short)s) << 16; return v.f;
}
__device__ __forceinline__ short f2bf(float f) {
    union { float f; unsigned u; } v; v.f = f;
    unsigned r = v.u + 0x7fff + ((v.u >> 16) & 1);  // round-to-nearest-even
    return (short)(r >> 16);
}
__device__ __forceinline__ float sigmoidf_(float x) {
    float xc = fminf(fmaxf(x, -30.f), 30.f);
    return 1.f / (1.f + __expf(-xc));
}
__device__ __forceinline__ float tanhf_(float x) {
    float xc = fminf(fmaxf(x, -15.f), 15.f);
    float e = __expf(2.f * xc);
    return (e - 1.f) / (e + 1.f);
}
__device__ __forceinline__ int aload(const int* p) {
    return __hip_atomic_load((int*)p, __ATOMIC_RELAXED, __HIP_MEMORY_SCOPE_AGENT);
}
__device__ __forceinline__ void astore(int* p, int v) {
    __hip_atomic_store(p, v, __ATOMIC_RELAXED, __HIP_MEMORY_SCOPE_AGENT);
}

// 64-block generation barrier (R8-verified; R5/R7/R11: ANY wider barrier
// pays 50-100us in cross-XCD L2 invalidate traffic). RELAXED polling by one
// lane per block with s_sleep; fences only at the crossing points.
__device__ __forceinline__ void gbar(int* bar, int phase, int tid) {
    __syncthreads();
    if (tid == 0) {
        __threadfence();
        __hip_atomic_fetch_add(bar, 1, __ATOMIC_ACQ_REL, __HIP_MEMORY_SCOPE_AGENT);
        while (aload(bar) < TAILB * phase)
            __builtin_amdgcn_s_sleep(8);
        __threadfence();
    }
    __syncthreads();
}

// Shared epilogue: fused LSTM cell update for one 128-row m-tile's
// accumulators (used by the 128^2 gates_tile inside tail_k).
// first=1 (t==0): cell is write-only (c = i*cg == f*0 + i*cg bit-exactly),
// so cell never needs zero-init and t=0 skips the 33.6MB cell read.
__device__ __forceinline__ void gates_epilogue(
    const float4v (&acc)[4][4], int m0, int bx, int wave, int lane, int first,
    const float* __restrict__ bias_g, float* __restrict__ cell,
    short* __restrict__ Sout, const int* __restrict__ ridx, int n_act)
{
    const int wm = wave & 1, wn = wave >> 1;
    const int colq = lane & 15, q = lane >> 4;
    const int G = bx * 2 + wn;   // 64-col group = 16 hidden units
    const int h = G * 16 + colq;
    const float bi  = bias_g[G * 64 +  0 + colq];
    const float bff = bias_g[G * 64 + 16 + colq];
    const float bc  = bias_g[G * 64 + 32 + colq];
    const float bo  = bias_g[G * 64 + 48 + colq];
#pragma unroll
    for (int i = 0; i < 4; ++i) {
        const int pbase = m0 + wm * 64 + i * 16 + q * 4;
#pragma unroll
        for (int r = 0; r < 4; ++r) {
            const int pos = pbase + r;
            if (pos < n_act) {
                const int row = ridx[pos];
                const float ig = sigmoidf_(acc[i][0][r] + bi);
                const float fg = sigmoidf_(acc[i][1][r] + bff);
                const float cg = tanhf_(acc[i][2][r] + bc);
                const float og = sigmoidf_(acc[i][3][r] + bo);
                const size_t ci = (size_t)row * HID + h;
                const float c = first ? (ig * cg) : (fg * cell[ci] + ig * cg);
                cell[ci] = c;
                Sout[(size_t)row * HID + h] = f2bf(og * tanhf_(c));
            }
        }
    }
}

// Gates GEMM, R18 = R14 body (best measured: 117.7us) + XCD swizzle.
// R13-R17 established schedule-insensitivity: 2-blocks/CU lockstep (127),
// 2-phase drain (117.7), zero-wait async (121.9), 4-phase fine interleave
// + setprio + counted vmcnt (122.5) all land at 575-625 TF. The R14 form
// is the simplest of the best. XCD-rectangle swizzle kept from R16
// (FETCH 95->69 MB verified, time-neutral): dispatch round-robins XCDs
// (lin&7); remapping each XCD to an 8x-by-4y rectangle makes its A/B
// panels L2-resident.
__global__ __launch_bounds__(512, 1) void gates_k(
    const short* __restrict__ S, const short* __restrict__ XB,
    const short* __restrict__ B,
    const float* __restrict__ bias_g, int nK, int hidK, int first,
    float* __restrict__ cell, short* __restrict__ Sout,
    const int* __restrict__ ridx, const int* __restrict__ cnt, int t)
{
    __shared__ short As[2][GTM * TK];   // 2 x 32 KiB
    __shared__ short Bs[2][GTN * TK];   // 2 x 32 KiB
    const int n_act = cnt[t];
    const int tid  = threadIdx.x;
    const int wave = tid >> 6, lane = tid & 63;
    const int wm2 = wave >> 2, wn4 = wave & 3;   // wave -> 128-row half x 64-col quarter
    const int colq = lane & 15, q = lane >> 4;
    const int lrow8 = lane >> 3;
    const int lk    = (((lane & 7) ^ lrow8) * 8);   // pre-swizzled source offset
    const int xq = colq & 7;
    const int abase = (wm2 * 128 + colq) * TK;   // shorts
    const int bbase = (wn4 * 64  + colq) * TK;   // shorts

    // XCD-rectangle swizzle (grid is 16x16 for all gates_k launches).
    int bx, byS;
    {
        const int lin  = (int)blockIdx.x + 16 * (int)blockIdx.y;  // hw order
        const int xcd  = lin & 7;          // round-robin XCD assignment
        const int slot = lin >> 3;         // 0..31 within this XCD
        bx  = (xcd & 1) * 8 + (slot & 7);  // 8 consecutive x per XCD
        byS = (xcd >> 1) * 4 + (slot >> 3);// 4 consecutive y per XCD
    }
    const int n0 = bx * GTN;

    for (int by = byS; by * GTM < n_act; by += 16) {
        const int m0 = by * GTM;

        // per-wave staged rows: wave*32 + it*8 + lrow8 (A and B share the map)
        int rows_[4];
        const short* gb[4];
#pragma unroll
        for (int it = 0; it < 4; ++it) {
            const int rr = wave * 32 + it * 8 + lrow8;
            rows_[it] = ridx[m0 + rr];
            gb[it] = B + (size_t)(n0 + rr) * KTOT + lk;
        }

        float4v acc[8][4];
#pragma unroll
        for (int i = 0; i < 8; ++i)
#pragma unroll
            for (int j = 0; j < 4; ++j) acc[i][j] = (float4v)0.f;

        auto stage = [&](int ki, int buf) {
            const int kk = ki * TK;
            const bool fromS = (kk < hidK);   // kernel-uniform branch
#pragma unroll
            for (int it = 0; it < 4; ++it) {
                const int dst = (wave * 32 + it * 8) * TK;
                const short* sa = fromS
                    ? (S  + (size_t)rows_[it] * HID    + kk + lk)
                    : (XB + (size_t)rows_[it] * IN_DIM + lk);
                __builtin_amdgcn_global_load_lds(
                    (const __attribute__((address_space(1))) void*)sa,
                    (__attribute__((address_space(3))) void*)(As[buf] + dst), 16, 0, 0);
                __builtin_amdgcn_global_load_lds(
                    (const __attribute__((address_space(1))) void*)(gb[it] + kk),
                    (__attribute__((address_space(3))) void*)(Bs[buf] + dst), 16, 0, 0);
            }
        };

        stage(0, 0);
        __syncthreads();   // drains prologue stage

        for (int ki = 0; ki < nK; ++ki) {
            const int cur = ki & 1;
            if (ki + 1 < nK) stage(ki + 1, cur ^ 1);   // issue BEFORE compute
            const short* Ac = As[cur];
            const short* Bc = Bs[cur];
#pragma unroll
            for (int c2 = 0; c2 < 2; ++c2) {
                const int xt = ((q + 4 * c2) ^ xq) << 3;
                short8 af[8], bf[4];
#pragma unroll
                for (int i = 0; i < 8; ++i)
                    af[i] = *(const short8*)(Ac + abase + i * (16 * TK) + xt);
#pragma unroll
                for (int j = 0; j < 4; ++j)
                    bf[j] = *(const short8*)(Bc + bbase + j * (16 * TK) + xt);
#pragma unroll
                for (int i = 0; i < 8; ++i)
#pragma unroll
                    for (int j = 0; j < 4; ++j)
                        acc[i][j] = __builtin_amdgcn_mfma_f32_16x16x32_bf16(af[i], bf[j], acc[i][j], 0, 0, 0);
            }
            // one barrier per K-step: lgkm (ds_reads) drained by MFMA deps,
            // vmcnt drained inside __syncthreads -> buf[cur^1] ready.
            __syncthreads();
        }

        // epilogue: per wave, cols n0 + wn4*64 .. +63 = one 64-col G-group
        // = all 4 gates of 16 hidden units (interleaved weight layout).
        const int G = bx * 4 + wn4;
        const int h = G * 16 + colq;
        const float bi  = bias_g[G * 64 +  0 + colq];
        const float bff = bias_g[G * 64 + 16 + colq];
        const float bc  = bias_g[G * 64 + 32 + colq];
        const float bo  = bias_g[G * 64 + 48 + colq];
#pragma unroll
        for (int i = 0; i < 8; ++i) {
            const int pbase = m0 + wm2 * 128 + i * 16 + q * 4;
#pragma unroll
            for (int r = 0; r < 4; ++r) {
                const int pos = pbase + r;
                if (pos < n_act) {
                    const int row = ridx[pos];
                    const float ig = sigmoidf_(acc[i][0][r] + bi);
                    const float fg = sigmoidf_(acc[i][1][r] + bff);
                    const float cg = tanhf_(acc[i][2][r] + bc);
                    const float og = sigmoidf_(acc[i][3][r] + bo);
                    const size_t ci = (size_t)row * HID + h;
                    const float c = first ? (ig * cg) : (fg * cell[ci] + ig * cg);
                    cell[ci] = c;
                    Sout[(size_t)row * HID + h] = f2bf(og * tanhf_(c));
                }
            }
        }
        // last K-iter ended in __syncthreads; epilogue touches no LDS;
        // next m-tile's stage(0,0) is followed by its own __syncthreads.
    }
}

// Single-m-tile gates (R10 form, split-A, 128^2) — used only inside tail_k.
__device__ __forceinline__ void gates_tile(
    short* As, short* Bs, int tid,
    const short* __restrict__ S, const short* __restrict__ XB,
    const short* __restrict__ B,
    const float* __restrict__ bias_g,
    float* __restrict__ cell, short* __restrict__ Sout,
    const int* __restrict__ ridx, int n_act, int m0, int bx)
{
    const int wave = tid >> 6, lane = tid & 63;
    const int wm = wave & 1, wn = wave >> 1;
    const int colq = lane & 15, q = lane >> 4;
    const int lrow8 = lane >> 3;
    const int lk    = (((lane & 7) ^ lrow8) * 8);
    const int n0 = bx * TN;

    int aoff[4][2], boff[4][2];
#pragma unroll
    for (int i = 0; i < 4; ++i) {
        const int Ra = wm * 64 + i * 16 + colq;
        const int Rb = wn * 64 + i * 16 + colq;
#pragma unroll
        for (int c2 = 0; c2 < 2; ++c2) {
            const int C = q + 4 * c2;
            aoff[i][c2] = Ra * TK + ((C ^ (Ra & 7)) << 3);
            boff[i][c2] = Rb * TK + ((C ^ (Rb & 7)) << 3);
        }
    }

    float4v acc[4][4];
#pragma unroll
    for (int i = 0; i < 4; ++i)
#pragma unroll
        for (int j = 0; j < 4; ++j) acc[i][j] = (float4v)0.f;

    const short* gaS[4];
    const short* gaX[4];
    const short* gb[4];
#pragma unroll
    for (int it = 0; it < 4; ++it) {
        const int rr = (wave * 4 + it) * 8;
        const int r0 = ridx[m0 + rr + lrow8];
        gaS[it] = S + (size_t)r0 * HID + lk;
        gaX[it] = XB + (size_t)r0 * IN_DIM + lk;
        gb[it]  = B + (size_t)(n0 + rr + lrow8) * KTOT + lk;
    }

    for (int ki = 0; ki < KTOT / TK; ++ki) {
        const bool fromS = (ki * TK < HID);
#pragma unroll
        for (int it = 0; it < 4; ++it) {
            const int rr = (wave * 4 + it) * 8;
            const short* a0 = fromS ? gaS[it] : gaX[it];
            __builtin_amdgcn_global_load_lds(
                (const __attribute__((address_space(1))) void*)a0,
                (__attribute__((address_space(3))) void*)(As + rr * TK), 16, 0, 0);
            __builtin_amdgcn_global_load_lds(
                (const __attribute__((address_space(1))) void*)gb[it],
                (__attribute__((address_space(3))) void*)(Bs + rr * TK), 16, 0, 0);
            gaS[it] += TK; gb[it] += TK;
        }
        __syncthreads();
#pragma unroll
        for (int c2 = 0; c2 < 2; ++c2) {
            short8 af[4], bf[4];
#pragma unroll
            for (int i = 0; i < 4; ++i) {
                af[i] = *(const short8*)(As + aoff[i][c2]);
                bf[i] = *(const short8*)(Bs + boff[i][c2]);
            }
#pragma unroll
            for (int i = 0; i < 4; ++i)
#pragma unroll
                for (int j = 0; j < 4; ++j)
                    acc[i][j] = __builtin_amdgcn_mfma_f32_16x16x32_bf16(af[i], bf[j], acc[i][j], 0, 0, 0);
        }
        __syncthreads();
    }

    gates_epilogue(acc, m0, bx, wave, lane, 0, bias_g, cell, Sout, ridx, n_act);
    __syncthreads();   // protect As/Bs before caller's next tile
}

// R18 midfin: 32-ROW TILES, full-machine parallelism. Old structure was
// 64 blocks x 128-row tiles = 1/4 of CUs at 1 wave/SIMD, drain-per-step
// -> est. 50-70us each for a 2.1 GF / 16MB-read memory-bound GEMM whose
// full-machine floor is ~3-5us. New: tile = 32 rows, 256 tiles at t=0/1
// -> 256 blocks (1/CU). Block = 4 waves; wave w owns a 32x32 output
// (cols w*32..+31) as 2x2 16x16x32 fragments, K=HID in 16 steps.
// A-tile [32][64] (4KB) + P-tile [128][64] (16KB) staged per step with
// the verified swizzled global_load_lds pattern (dst wave-uniform base,
// lane l -> row base+ (l>>3), chunk l&7; src pre-swizzled by lk).
// Epilogue: halt-dot (8 rows/wave, 64-lane shuffle dot), ReLU+W2 column
// reduce (shfl over colq within each 16-lane group), cross-wave combine
// via 128-float red[] in LDS, then 1 thread/row finalize + compaction.
// acc row mapping (C/D layout): out-row = mi*16 + q*4 + r.
__device__ __forceinline__ void midfin_tile(
    short* As, short* Bs, int tid,
    const short* __restrict__ Snew, const short* __restrict__ P,
    const float* __restrict__ bias_p, const float* __restrict__ W_halt,
    const float* __restrict__ W2, const float* __restrict__ b2,
    float* __restrict__ outp, float* __restrict__ p_sum,
    const int* __restrict__ rprev, int* __restrict__ rnext,
    int* __restrict__ cnt, int t, int m0, int n_act)
{
    const int wave = tid >> 6, lane = tid & 63;
    const int colq = lane & 15, q = lane >> 4;
    const int lrow8 = lane >> 3;
    const int lk    = (((lane & 7) ^ lrow8) * 8);
    const int xq = colq & 7;

    float4v acc[2][2];
#pragma unroll
    for (int mi = 0; mi < 2; ++mi)
#pragma unroll
        for (int nj = 0; nj < 2; ++nj) acc[mi][nj] = (float4v)0.f;

    // per-lane source rows (dummy row 0 for padded positions is in-range)
    const short* ga = Snew + (size_t)rprev[m0 + wave * 8 + lrow8] * HID + lk;
    const short* gbp[4];
#pragma unroll
    for (int g = 0; g < 4; ++g)
        gbp[g] = P + (size_t)(wave * 32 + g * 8 + lrow8) * HID + lk;

    for (int k0 = 0; k0 < HID; k0 += TK) {
        // stage A rows wave*8..+7 (1 instr/wave) + P rows wave*32..+31 (4)
        __builtin_amdgcn_global_load_lds(
            (const __attribute__((address_space(1))) void*)(ga + k0),
            (__attribute__((address_space(3))) void*)(As + (wave * 8) * TK), 16, 0, 0);
#pragma unroll
        for (int g = 0; g < 4; ++g)
            __builtin_amdgcn_global_load_lds(
                (const __attribute__((address_space(1))) void*)(gbp[g] + k0),
                (__attribute__((address_space(3))) void*)(Bs + (wave * 32 + g * 8) * TK), 16, 0, 0);
        __syncthreads();
#pragma unroll
        for (int c2 = 0; c2 < 2; ++c2) {
            const int xt = ((q + 4 * c2) ^ xq) << 3;
            short8 af[2], bf[2];
#pragma unroll
            for (int mi = 0; mi < 2; ++mi)
                af[mi] = *(const short8*)(As + (mi * 16 + colq) * TK + xt);
#pragma unroll
            for (int nj = 0; nj < 2; ++nj)
                bf[nj] = *(const short8*)(Bs + (wave * 32 + nj * 16 + colq) * TK + xt);
#pragma unroll
            for (int mi = 0; mi < 2; ++mi)
#pragma unroll
                for (int nj = 0; nj < 2; ++nj)
                    acc[mi][nj] = __builtin_amdgcn_mfma_f32_16x16x32_bf16(af[mi], bf[nj], acc[mi][nj], 0, 0, 0);
        }
        __syncthreads();
    }

    // aliases over As (k-loop done; last barrier above protects)
    float* red  = (float*)As;           // 128 floats: [w][mi][q][r]
    float* hbuf = ((float*)As) + 128;   // 32 floats

    // halt-dot: 8 rows per wave, whole-wave dot over 1024 elems
#pragma unroll
    for (int s = 0; s < 8; ++s) {
        const int lr = wave * 8 + s;
        const int row = rprev[m0 + lr];
        const short* Ar = Snew + (size_t)row * HID + lane * 16;
        const short8 v0 = *(const short8*)Ar;
        const short8 v1 = *(const short8*)(Ar + 8);
        const float* Wh = W_halt + lane * 16;
        float hv = 0.f;
#pragma unroll
        for (int e = 0; e < 8; ++e) hv += bf2f(v0[e]) * Wh[e];
#pragma unroll
        for (int e = 0; e < 8; ++e) hv += bf2f(v1[e]) * Wh[8 + e];
#pragma unroll
        for (int o = 32; o > 0; o >>= 1) hv += __shfl_down(hv, o);
        if (lane == 0) hbuf[lr] = hv;
    }

    // relu + W2-dot over this wave's 32 cols, reduce over colq
    float pr[2][4];
#pragma unroll
    for (int mi = 0; mi < 2; ++mi)
#pragma unroll
        for (int r = 0; r < 4; ++r) pr[mi][r] = 0.f;
#pragma unroll
    for (int nj = 0; nj < 2; ++nj) {
        const int col = wave * 32 + nj * 16 + colq;
        const float b = bias_p[col];
        const float w2 = W2[col];
#pragma unroll
        for (int mi = 0; mi < 2; ++mi)
#pragma unroll
            for (int r = 0; r < 4; ++r)
                pr[mi][r] += fmaxf(acc[mi][nj][r] + b, 0.f) * w2;
    }
#pragma unroll
    for (int mi = 0; mi < 2; ++mi)
#pragma unroll
        for (int r = 0; r < 4; ++r) {
            float v = pr[mi][r];
            v += __shfl_down(v, 8, 16);
            v += __shfl_down(v, 4, 16);
            v += __shfl_down(v, 2, 16);
            v += __shfl_down(v, 1, 16);
            if (colq == 0)
                red[((wave * 2 + mi) * 4 + q) * 4 + r] = v;
        }
    __syncthreads();

    // finalize: one thread per row (32 rows)
    if (tid < TMF) {
        const int pos = m0 + tid;
        if (pos < n_act) {
            const int mi = tid >> 4, lq = (tid >> 2) & 3, r = tid & 3;
            float odot = 0.f;
#pragma unroll
            for (int w = 0; w < 4; ++w)
                odot += red[((w * 2 + mi) * 4 + lq) * 4 + r];
            const int row = rprev[pos];
            const float ov = sigmoidf_(odot + b2[0]);
            const float h  = sigmoidf_(hbuf[tid] + bias_p[OMID]);
            const float ps = p_sum[row];
            const float pn = ps + h;
            const bool fin = (pn >= 1.f - 1e-3f) || (t == MAX_ITER - 1);
            const float halt = fin ? (1.f - ps) : h;
            outp[row] += ov * halt;
            p_sum[row] = fin ? 1.f : pn;
            if (!fin) {
                const int d = atomicAdd(&cnt[t + 1], 1);
                astore(&rnext[d], row);
            }
        }
    }
    __syncthreads();   // protect As/Bs aliases before caller reuses LDS
}

// Standalone midfin dispatch (steps 0..1): 256 blocks x 32-row tiles.
__global__ __launch_bounds__(256) void midfin_k(
    const short* __restrict__ Snew, const short* __restrict__ P,
    const float* __restrict__ bias_p, const float* __restrict__ W_halt,
    const float* __restrict__ W2, const float* __restrict__ b2,
    float* __restrict__ outp, float* __restrict__ p_sum,
    const int* __restrict__ rprev, int* __restrict__ rnext,
    int* __restrict__ cnt, int t)
{
    __shared__ short As[TM * TK];
    __shared__ short Bs[TN * TK];
    const int n_act = cnt[t];
    for (int tile = blockIdx.x; tile * TMF < n_act; tile += gridDim.x)
        midfin_tile(As, Bs, threadIdx.x, Snew, P, bias_p, W_halt, W2, b2,
                    outp, p_sum, rprev, rnext, cnt, t, tile * TMF, n_act);
}

// Persistent 64-block tail: midfin(2) + steps 3..7 (gates+midfin) with
// in-kernel barriers. For this data cnt[3]==0 so the generic loop exits
// after midfin(2)+1 barrier; full loop retained for arbitrary data.
// midfin now 32-row tiles: t=2's ~4096 rows -> 128 tiles over 64 blocks
// (was 32/64 = half the blocks idle).
__global__ __launch_bounds__(256) void tail_k(
    const short* __restrict__ Wg, const float* __restrict__ bias_g,
    const short* __restrict__ P, const float* __restrict__ bias_p,
    const float* __restrict__ W_halt, const float* __restrict__ W2,
    const float* __restrict__ b2,
    short* __restrict__ S0, short* __restrict__ S1,
    const short* __restrict__ XB,
    float* __restrict__ cell, float* __restrict__ outp,
    float* __restrict__ p_sum,
    int* __restrict__ ridx0, int* __restrict__ ridx1,
    int* __restrict__ cnt, int* __restrict__ bar)
{
    __shared__ short As[TM * TK];
    __shared__ short Bs[TN * TK];
    const int tid = threadIdx.x;
    int phase = 0;
    int t = 2;
    while (true) {
        short* Snew = (t & 1) ? S0 : S1;        // state written by gates(t)
        const int* rprev = (t & 1) ? ridx1 : ridx0;  // L_t
        int* rnext = (t & 1) ? ridx0 : ridx1;        // L_{t+1}
        const int n = aload(&cnt[t]);
        for (int tile = blockIdx.x; tile * TMF < n; tile += gridDim.x)
            midfin_tile(As, Bs, tid, Snew, P, bias_p, W_halt, W2, b2,
                        outp, p_sum, rprev, rnext, cnt, t, tile * TMF, n);
        if (t == MAX_ITER - 1) break;
        ++phase; gbar(bar, phase, tid);          // publish cnt[t+1], ridx, p_sum
        const int n1 = aload(&cnt[t + 1]);
        if (n1 == 0) break;                      // uniform across blocks
        {
            short* Sot = (t & 1) ? S1 : S0;
            const int ntiles = ((n1 + TM - 1) / TM) * (NGATES / TN);
            for (int e = blockIdx.x; e < ntiles; e += gridDim.x)
                gates_tile(As, Bs, tid, Snew, XB, Wg, bias_g, cell, Sot,
                           rnext, n1, (e >> 5) * TM, e & 31);
        }
        ++phase; gbar(bar, phase, tid);          // publish Sout, cell
        ++t;
    }
}

// one dispatch for all setup: weight packing + XB + bookkeeping init.
// NOTE: S0/S1/cell are deliberately NOT initialized — at t=0 all rows are
// active, so gates(0) writes every state/cell entry before any read.
#define SETUP_XB    (BATCH * IN_DIM)
#define SETUP_WG    (NGATES * KTOT)
#define SETUP_P     (NP * HID)
#define SETUP_TOT   (SETUP_XB + SETUP_WG + SETUP_P)
__global__ __launch_bounds__(256) void setup_k(
    const float* __restrict__ x,
    const float* __restrict__ Whi, const float* __restrict__ Whf,
    const float* __restrict__ Whc, const float* __restrict__ Who,
    const float* __restrict__ Wxi, const float* __restrict__ Wxf,
    const float* __restrict__ Wxc, const float* __restrict__ Wxo,
    const float* __restrict__ bxi, const float* __restrict__ bhi,
    const float* __restrict__ bxf, const float* __restrict__ bhf,
    const float* __restrict__ bxc, const float* __restrict__ bhc,
    const float* __restrict__ bxo, const float* __restrict__ bho,
    const float* __restrict__ W1, const float* __restrict__ b1,
    const float* __restrict__ W_halt, const float* __restrict__ b_halt,
    short* __restrict__ XB,
    float* __restrict__ p_sum,
    int* __restrict__ ridx0, int* __restrict__ ridx1, int* __restrict__ cnt,
    int* __restrict__ bar, float* __restrict__ outp,
    short* __restrict__ Wg, float* __restrict__ bias_g,
    short* __restrict__ P, float* __restrict__ bias_p)
{
    int idx = blockIdx.x * 256 + threadIdx.x;
    if (idx < SETUP_XB) {
        const int row = idx >> 6, k = idx & 63;
        XB[idx] = f2bf(x[idx]);
        if (k == 0) {
            p_sum[row] = 0.f;
            outp[row] = 0.f;
            ridx0[row] = row;   // step 0: identity compaction
            ridx1[row] = 0;     // in-range dummies for padded tile reads
        }
        if (row == 0 && k <= MAX_ITER) cnt[k] = (k == 0) ? BATCH : 0;
        if (row == 1 && k == 0) bar[0] = 0;
        return;
    }
    idx -= SETUP_XB;
    if (idx < SETUP_WG) {
        const int n = idx / KTOT, k = idx - n * KTOT;
        // interleaved layout: n = 64*G + 16*g + q  ->  gate g of hidden h=16*G+q
        const int G = n >> 6, g = (n >> 4) & 3, q = n & 15;
        const int h = G * 16 + q;
        const float* Wh = (g == 0) ? Whi : (g == 1) ? Whf : (g == 2) ? Whc : Who;
        const float* Wx = (g == 0) ? Wxi : (g == 1) ? Wxf : (g == 2) ? Wxc : Wxo;
        const float v = (k < HID) ? Wh[h * HID + k] : Wx[h * IN_DIM + (k - HID)];
        Wg[idx] = f2bf(v);
        if (k == 0) {
            const float* bx = (g == 0) ? bxi : (g == 1) ? bxf : (g == 2) ? bxc : bxo;
            const float* bh = (g == 0) ? bhi : (g == 1) ? bhf : (g == 2) ? bhc : bho;
            bias_g[n] = bx[h] + bh[h];
        }
        return;
    }
    idx -= SETUP_WG;
    if (idx < SETUP_P) {
        const int n = idx >> 10, k = idx & 1023;
        const float v = (n < OMID) ? W1[n * HID + k] : (n == OMID ? W_halt[k] : 0.f);
        P[idx] = f2bf(v);
        if (k == 0) bias_p[n] = (n < OMID) ? b1[n] : (n == OMID ? b_halt[0] : 0.f);
    }
}

extern "C" void kernel_launch(void* const* d_in, const int* in_sizes, int n_in,
                              void* d_out, int out_size, void* d_ws, size_t ws_size,
                              hipStream_t stream) {
    const float* x    = (const float*)d_in[0];
    const float* Wxi  = (const float*)d_in[1];
    const float* bxi  = (const float*)d_in[2];
    const float* Whi  = (const float*)d_in[3];
    const float* bhi  = (const float*)d_in[4];
    const float* Wxf  = (const float*)d_in[5];
    const float* bxf  = (const float*)d_in[6];
    const float* Whf  = (const float*)d_in[7];
    const float* bhf  = (const float*)d_in[8];
    const float* Wxc  = (const float*)d_in[9];
    const float* bxc  = (const float*)d_in[10];
    const float* Whc  = (const float*)d_in[11];
    const float* bhc  = (const float*)d_in[12];
    const float* Wxo  = (const float*)d_in[13];
    const float* bxo  = (const float*)d_in[14];
    const float* Who  = (const float*)d_in[15];
    const float* bho  = (const float*)d_in[16];
    const float* W_halt = (const float*)d_in[17];
    const float* b_halt = (const float*)d_in[18];
    const float* W1   = (const float*)d_in[19];
    const float* b1   = (const float*)d_in[20];
    const float* W2   = (const float*)d_in[21];
    const float* b2   = (const float*)d_in[22];

    char* p = (char*)d_ws;
    auto carve = [&](size_t bytes) { char* r = p; p += (bytes + 255) & ~(size_t)255; return r; };
    short* S0     = (short*)carve((size_t)BATCH * HID * 2);
    short* S1     = (short*)carve((size_t)BATCH * HID * 2);
    short* XB     = (short*)carve((size_t)BATCH * IN_DIM * 2);
    short* Wg     = (short*)carve((size_t)NGATES * KTOT * 2);
    float* bias_g = (float*)carve((size_t)NGATES * 4);
    short* P      = (short*)carve((size_t)NP * HID * 2);
    float* bias_p = (float*)carve((size_t)NP * 4);
    float* cell   = (float*)carve((size_t)BATCH * HID * 4);
    float* p_sum  = (float*)carve((size_t)BATCH * 4);
    int*   ridx0  = (int*)carve((size_t)BATCH * 4);
    int*   ridx1  = (int*)carve((size_t)BATCH * 4);
    int*   cnt    = (int*)carve((size_t)(MAX_ITER + 1) * 4);
    int*   bar    = (int*)carve(256);
    float* outp   = (float*)d_out;

    setup_k<<<(SETUP_TOT + 255) / 256, 256, 0, stream>>>(
        x, Whi, Whf, Whc, Who, Wxi, Wxf, Wxc, Wxo,
        bxi, bhi, bxf, bhf, bxc, bhc, bxo, bho,
        W1, b1, W_halt, b_halt,
        XB, p_sum, ridx0, ridx1, cnt, bar, outp,
        Wg, bias_g, P, bias_p);

    // t=0: state==0 -> x-part only (1 k-iter from XB), cell write-only
    gates_k<<<dim3(16, 16), 512, 0, stream>>>(
        S0, XB, Wg + HID, bias_g, 1, 0, 1, cell, S1, ridx0, cnt, 0);
    midfin_k<<<256, 256, 0, stream>>>(
        S1, P, bias_p, W_halt, W2, b2, outp, p_sum, ridx0, ridx1, cnt, 0);
    // t=1: full batch (32 m-tiles of 256 -> 2 per y-block)
    gates_k<<<dim3(16, 16), 512, 0, stream>>>(
        S1, XB, Wg, bias_g, KTOT / TK, HID, 0, cell, S0, ridx1, cnt, 1);
    midfin_k<<<256, 256, 0, stream>>>(
        S0, P, bias_p, W_halt, W2, b2, outp, p_sum, ridx1, ridx0, cnt, 1);
    // t=2: ~half batch (16 m-tiles -> 1 per y-block)
    gates_k<<<dim3(16, 16), 512, 0, stream>>>(
        S0, XB, Wg, bias_g, KTOT / TK, HID, 0, cell, S1, ridx0, cnt, 2);
    // midfin(2) + steps 3..7 in one persistent 64-block kernel
    tail_k<<<TAILB, 256, 0, stream>>>(
        Wg, bias_g, P, bias_p, W_halt, W2, b2,
        S0, S1, XB, cell, outp, p_sum, ridx0, ridx1, cnt, bar);
}